// Round 11
// baseline (190.901 us; speedup 1.0000x reference)
//
#include <hip/hip_runtime.h>

// PositionWiseSpatialAttention — fused flash-style kernel, MI355X gfx950.
//
// R16 = R15 (R13 structure + setprio) with ONE surgical change: the 8 W
// fragment ds_read_b128s are hoisted from inside the PW loop to BETWEEN the
// QK^T MFMA cluster and the exp phase. The exp/split VALU (~120 cyc) covers
// their latency; PW then issues with operands ready. This is the minimal
// version of R14's idea: R14 hoisted K arrays + W across the whole QK burst
// (+64 VGPR long-lived) and the compiler spilled to scratch (WRITE_SIZE
// 24.6->59.9 MB) despite headroom; here the live range is only the exp
// phase (+32 VGPR short-lived, peak ~116 <= 170 budget at 3 waves/SIMD).
// PRIMARY CHECK: WRITE_SIZE must stay ~24.6 MB (no spill); if it balloons,
// R15 is the final answer. Math identical -> absmax bit-identical.

#define NB    8
#define NT    12
#define NNODE 1024
#define ND    64
#define XROW  768   /* NT*ND: stride between consecutive n for fixed (b,t) */
#define NG    96    /* NB*NT */

typedef __bf16 bf16x8 __attribute__((ext_vector_type(8)));
typedef __bf16 bf16x4 __attribute__((ext_vector_type(4)));
typedef float  floatx4 __attribute__((ext_vector_type(4)));

#define MFMA(a,b,c) __builtin_amdgcn_mfma_f32_16x16x32_bf16((a),(b),(c),0,0,0)

#define QSCALE 0.18033688011112042f   /* 0.125 * log2(e) */

// Per-buffer LDS layout (bytes); two buffers for the main kernel.
#define KSTRIDE 72   /* bf16 per K row: 144 B */
#define VSTRIDE 40   /* bf16 per W row:  80 B */
#define OFF_KHI 0
#define OFF_KLO 4608
#define OFF_WHI 9216
#define OFF_WLO 14336
#define BUFSZ   19456
#define SMEM8   (2 * BUFSZ)               /* 38912 */
// fallback (R5) LDS map
#define PSTRIDE 36
#define AGSTRIDE 68
#define OFF_VHI 9216
#define OFF_VLO 14336
#define OFF_P   19456
#define SMEM_FB (19456 + 128*PSTRIDE*4)   /* 37888 */

// workspace element offsets (__bf16 units)
#define WXHI  0          /* [96][1024][64] row-major hi           */
#define WXLO  6291456
#define WVPHI 12582912   /* [96][64 o][1024] W^T permuted hi       */
#define WVPLO 18874368
#define WS_BYTES 50348032ULL

struct bfpair { __bf16 h, l; };

// error-compensated split: hi = RNE(f) via native fptrunc, lo = RNE(f - hi).
__device__ __forceinline__ bfpair split1(float f) {
    bfpair r;
    __bf16 hb = (__bf16)f;
    float hf = __builtin_bit_cast(float,
                   (unsigned)__builtin_bit_cast(unsigned short, hb) << 16);
    r.h = hb;
    r.l = (__bf16)(f - hf);
    return r;
}

// ---------------------------------------------------------------------------
// presplit: grid 1536 (96 g x 16 n-blocks), 256 threads. (R13, verified)
// Phase A: x tile -> T (LDS) + row-major split -> Xhi/Xlo.
// Phase B: W = T · Θ via 3-term split-bf16 MFMA -> Wt (LDS, f32).
// Phase C: transposed+PERMUTED split of Wt -> WVPhi/lo.
//   Position c in each 32-key tile holds key k(c)=((c&7)>>2)*16+(c>>3)*4+(c&3).
// ---------------------------------------------------------------------------
__global__ void __launch_bounds__(256)
presplit(const float* __restrict__ x, const float* __restrict__ theta,
         __bf16* __restrict__ ws)
{
    __shared__ __align__(16) float T[64 * 68];
    __shared__ __align__(16) float Wt[64 * 68];
    const int tid  = threadIdx.x;
    const int lane = tid & 63;
    const int wave = tid >> 6;
    const int l16  = lane & 15;
    const int quad = lane >> 4;
    const int bx   = blockIdx.x;
    const int g    = bx >> 4;
    const int nblk = bx & 15;
    const int bb   = g / NT;
    const int tt   = g - bb * NT;
    const int n0   = nblk * 64;

    __bf16* Xhi  = ws + WXHI  + (size_t)g * 65536;
    __bf16* Xlo  = ws + WXLO  + (size_t)g * 65536;
    __bf16* WPhi = ws + WVPHI + (size_t)g * 65536;
    __bf16* WPlo = ws + WVPLO + (size_t)g * 65536;
    const float* xg = x + (size_t)bb * (NNODE * XROW) + (size_t)tt * ND;

    // ---- Phase A: 64x64 fp32 tile -> T + row-major split ----
    #pragma unroll
    for (int i = 0; i < 4; ++i) {
        int chunk = i * 256 + tid;        // 0..1023
        int n  = chunk >> 4;              // 0..63
        int c4 = (chunk & 15) * 4;        // 0..60
        floatx4 f = *(const floatx4*)(xg + (size_t)(n0 + n) * XROW + c4);
        *(floatx4*)(T + n * 68 + c4) = f;
        bf16x4 h, l;
        #pragma unroll
        for (int j = 0; j < 4; ++j) {
            bfpair p = split1(f[j]); h[j] = p.h; l[j] = p.l;
        }
        *(bf16x4*)(Xhi + (size_t)(n0 + n) * 64 + c4) = h;
        *(bf16x4*)(Xlo + (size_t)(n0 + n) * 64 + c4) = l;
    }
    __syncthreads();

    // ---- Phase B: W = T · Θ (3-term split-bf16 MFMA), wave owns 16 keys ----
    {
        bf16x8 tah[2], tal[2];
        #pragma unroll
        for (int ks = 0; ks < 2; ++ks)
            #pragma unroll
            for (int j = 0; j < 8; ++j) {
                bfpair p = split1(T[(wave*16 + l16)*68 + ks*32 + quad*8 + j]);
                tah[ks][j] = p.h; tal[ks][j] = p.l;
            }
        const floatx4 vz = {0.f, 0.f, 0.f, 0.f};
        #pragma unroll
        for (int ot = 0; ot < 4; ++ot) {
            bf16x8 thb[2], tlb[2];
            #pragma unroll
            for (int ks = 0; ks < 2; ++ks)
                #pragma unroll
                for (int j = 0; j < 8; ++j) {
                    bfpair p = split1(theta[(size_t)(ks*32 + quad*8 + j) * ND
                                            + ot*16 + l16]);
                    thb[ks][j] = p.h; tlb[ks][j] = p.l;
                }
            floatx4 Wc = vz;
            #pragma unroll
            for (int ks = 0; ks < 2; ++ks) {
                Wc = MFMA(tah[ks], thb[ks], Wc);
                Wc = MFMA(tal[ks], thb[ks], Wc);
                Wc = MFMA(tah[ks], tlb[ks], Wc);
            }
            #pragma unroll
            for (int r = 0; r < 4; ++r)
                Wt[(wave*16 + quad*4 + r)*68 + ot*16 + l16] = Wc[r];
        }
    }
    __syncthreads();

    // ---- Phase C: transposed + permuted split of Wt (verified code) ----
    {
        const int o  = tid >> 2;          // 0..63
        const int nc = (tid & 3) * 16;    // 0..48 (dst positions nc..nc+15)
        const int tb = nc & 32;           // 32-key tile base within the 64-blk
        bf16x8 h0, l0, h1, l1;
        #pragma unroll
        for (int j = 0; j < 8; ++j) {
            int c0 = (nc & 31) + j;       // dst position in tile
            int k0 = ((c0 & 7) >> 2) * 16 + (c0 >> 3) * 4 + (c0 & 3);
            bfpair p = split1(Wt[(tb + k0) * 68 + o]);
            h0[j] = p.h; l0[j] = p.l;
            int c1 = (nc & 31) + 8 + j;
            int k1 = ((c1 & 7) >> 2) * 16 + (c1 >> 3) * 4 + (c1 & 3);
            bfpair q = split1(Wt[(tb + k1) * 68 + o]);
            h1[j] = q.h; l1[j] = q.l;
        }
        __bf16* dsth = WPhi + (size_t)o * NNODE + n0 + nc;
        __bf16* dstl = WPlo + (size_t)o * NNODE + n0 + nc;
        *(bf16x8*)dsth = h0; *(bf16x8*)(dsth + 8) = h1;
        *(bf16x8*)dstl = l0; *(bf16x8*)(dstl + 8) = l1;
    }
}

// ---------------------------------------------------------------------------
// spattn11: grid 768 (bx = rblk*96 + g), 256 threads, 4 waves x 32 rows.
// R15 loop body; W frag reads hoisted between QK^T cluster and exp phase.
// ---------------------------------------------------------------------------
__global__ void __launch_bounds__(256, 3)
spattn11(const __bf16* __restrict__ ws, const float* __restrict__ adj,
         float* __restrict__ out)
{
    __shared__ __align__(16) char smem[SMEM8];

    const int tid  = threadIdx.x;
    const int wave = tid >> 6;          // 0..3, owns rows wave*32..+31
    const int lane = tid & 63;
    const int l16  = lane & 15;
    const int quad = lane >> 4;

    // bx = rblk*96 + g: all 8 row-blocks of a g share bx%8 -> same XCD.
    const int bx   = blockIdx.x;
    const int g    = bx % NG;           // 0..95
    const int rblk = bx / NG;           // 0..7
    const int bb   = g / NT;
    const int tt   = g - bb * NT;
    const int row0 = rblk * 128;

    const __bf16* xh  = ws + WXHI  + (size_t)g * 65536;
    const __bf16* xl  = ws + WXLO  + (size_t)g * 65536;
    const __bf16* wph = ws + WVPHI + (size_t)g * 65536;
    const __bf16* wpl = ws + WVPLO + (size_t)g * 65536;

    // ---- Q fragments b128 from row-major split arrays (B operand) ----
    bf16x8 qhi[2][2], qlo[2][2];
    #pragma unroll
    for (int mt = 0; mt < 2; ++mt) {
        const __bf16* q0 = xh + (size_t)(row0 + wave*32 + mt*16 + l16) * 64 + quad*8;
        const __bf16* q1 = xl + (size_t)(row0 + wave*32 + mt*16 + l16) * 64 + quad*8;
        #pragma unroll
        for (int ks = 0; ks < 2; ++ks) {
            qhi[mt][ks] = *(const bf16x8*)(q0 + ks*32);
            qlo[mt][ks] = *(const bf16x8*)(q1 + ks*32);
        }
    }

    const floatx4 vzero = {0.f, 0.f, 0.f, 0.f};
    floatx4 acc[2][4];
    #pragma unroll
    for (int mt = 0; mt < 2; ++mt)
        #pragma unroll
        for (int dt = 0; dt < 4; ++dt)
            acc[mt][dt] = vzero;
    float lpart[2] = {0.f, 0.f};        // per-lane partial: q = l16 (per mt)

    // staging maps (verified geometry)
    const int skey = tid >> 3;          // 0..31
    const int sd0  = (tid & 7) * 8;     // 0..56
    const int svd  = tid >> 2;          // 0..63 (o-row of W^T)
    const int svk0 = (tid & 3) * 8;     // 0..24

    // prologue: stage tile 0 into buffer 0, prefetch tile 1 into regs
    bf16x8 kh, kl, wh, wl;
    kh = *(const bf16x8*)(xh  + (size_t)skey * 64 + sd0);
    kl = *(const bf16x8*)(xl  + (size_t)skey * 64 + sd0);
    wh = *(const bf16x8*)(wph + (size_t)svd * NNODE + svk0);
    wl = *(const bf16x8*)(wpl + (size_t)svd * NNODE + svk0);
    {
        char* b0 = smem;
        *(bf16x8*)((__bf16*)(b0 + OFF_KHI) + skey*KSTRIDE + sd0) = kh;
        *(bf16x8*)((__bf16*)(b0 + OFF_KLO) + skey*KSTRIDE + sd0) = kl;
        *(bf16x8*)((__bf16*)(b0 + OFF_WHI) + svd*VSTRIDE + svk0) = wh;
        *(bf16x8*)((__bf16*)(b0 + OFF_WLO) + svd*VSTRIDE + svk0) = wl;
    }
    kh = *(const bf16x8*)(xh  + (size_t)(32 + skey) * 64 + sd0);
    kl = *(const bf16x8*)(xl  + (size_t)(32 + skey) * 64 + sd0);
    wh = *(const bf16x8*)(wph + (size_t)svd * NNODE + 32 + svk0);
    wl = *(const bf16x8*)(wpl + (size_t)svd * NNODE + 32 + svk0);

    int cur = 0;
    for (int ct = 0; ct < 32; ++ct) {
        const int key0 = ct * 32;
        __syncthreads();   // all waves done reading buf[cur^1] (tile ct-1);
                           // buf[cur] (tile ct) writes now visible
        if (ct < 31) {     // write tile ct+1 into the dead buffer
            char* wb = smem + (cur ^ 1) * BUFSZ;
            *(bf16x8*)((__bf16*)(wb + OFF_KHI) + skey*KSTRIDE + sd0) = kh;
            *(bf16x8*)((__bf16*)(wb + OFF_KLO) + skey*KSTRIDE + sd0) = kl;
            *(bf16x8*)((__bf16*)(wb + OFF_WHI) + svd*VSTRIDE + svk0) = wh;
            *(bf16x8*)((__bf16*)(wb + OFF_WLO) + svd*VSTRIDE + svk0) = wl;
        }
        if (ct < 30) {     // prefetch tile ct+2 into regs (overlaps compute)
            const int nk = key0 + 64;
            kh = *(const bf16x8*)(xh  + (size_t)(nk + skey) * 64 + sd0);
            kl = *(const bf16x8*)(xl  + (size_t)(nk + skey) * 64 + sd0);
            wh = *(const bf16x8*)(wph + (size_t)svd * NNODE + nk + svk0);
            wl = *(const bf16x8*)(wpl + (size_t)svd * NNODE + nk + svk0);
        }
        // adj: float4 loads; lane l16 = q-row, quad*4+r = key within nt-tile
        floatx4 av[2][2];
        #pragma unroll
        for (int mt = 0; mt < 2; ++mt)
            #pragma unroll
            for (int nt = 0; nt < 2; ++nt)
                av[mt][nt] = *(const floatx4*)(adj
                    + (size_t)(row0 + wave*32 + mt*16 + l16) * NNODE
                    + key0 + nt*16 + quad*4);

        char* rb = smem + cur * BUFSZ;
        __bf16* Khi = (__bf16*)(rb + OFF_KHI);
        __bf16* Klo = (__bf16*)(rb + OFF_KLO);
        __bf16* Whi = (__bf16*)(rb + OFF_WHI);
        __bf16* Wlo = (__bf16*)(rb + OFF_WLO);

        // ---- S^T = K Q^T (swapped operands; 3-term split bf16) ----
        // Output: col = q = l16, row = key = nt*16 + quad*4 + r.
        floatx4 S[2][2] = {{vzero, vzero}, {vzero, vzero}};   // [mt][nt]
        __builtin_amdgcn_s_setprio(1);
        #pragma unroll
        for (int ks = 0; ks < 2; ++ks) {
            #pragma unroll
            for (int nt = 0; nt < 2; ++nt) {
                bf16x8 ah = *(const bf16x8*)(Khi + (nt*16 + l16)*KSTRIDE + ks*32 + quad*8);
                bf16x8 al = *(const bf16x8*)(Klo + (nt*16 + l16)*KSTRIDE + ks*32 + quad*8);
                #pragma unroll
                for (int mt = 0; mt < 2; ++mt) {
                    S[mt][nt] = MFMA(ah, qhi[mt][ks], S[mt][nt]);
                    S[mt][nt] = MFMA(ah, qlo[mt][ks], S[mt][nt]);
                    S[mt][nt] = MFMA(al, qhi[mt][ks], S[mt][nt]);
                }
            }
        }
        __builtin_amdgcn_s_setprio(0);

        // ---- W frag reads issued HERE: latency covered by the exp phase ----
        bf16x8 wvh[4], wvl[4];
        #pragma unroll
        for (int dt = 0; dt < 4; ++dt) {
            wvh[dt] = *(const bf16x8*)(Whi + (dt*16 + l16)*VSTRIDE + quad*8);
            wvl[dt] = *(const bf16x8*)(Wlo + (dt*16 + l16)*VSTRIDE + quad*8);
        }

        // ---- exp2 + adj-mask + split, ALL in registers ----
        bf16x8 pah[2], pal[2];
        #pragma unroll
        for (int mt = 0; mt < 2; ++mt)
            #pragma unroll
            for (int nt = 0; nt < 2; ++nt)
                #pragma unroll
                for (int r = 0; r < 4; ++r) {
                    float w = __builtin_amdgcn_exp2f(S[mt][nt][r] * QSCALE);
                    lpart[mt] += w;
                    bfpair pp = split1(av[mt][nt][r] * w);
                    pah[mt][nt*4 + r] = pp.h;
                    pal[mt][nt*4 + r] = pp.l;
                }

        // ---- acc += P . W (3-term split; W B-frags already in regs) ----
        __builtin_amdgcn_s_setprio(1);
        #pragma unroll
        for (int dt = 0; dt < 4; ++dt) {
            #pragma unroll
            for (int mt = 0; mt < 2; ++mt) {
                acc[mt][dt] = MFMA(pah[mt], wvh[dt], acc[mt][dt]);
                acc[mt][dt] = MFMA(pal[mt], wvh[dt], acc[mt][dt]);
                acc[mt][dt] = MFMA(pah[mt], wvl[dt], acc[mt][dt]);
            }
        }
        __builtin_amdgcn_s_setprio(0);
        cur ^= 1;
    }

    // ---- denominator: reduce across quads (each lane has q = l16) ----
    float linv[2][4];
    #pragma unroll
    for (int mt = 0; mt < 2; ++mt) {
        float lv = lpart[mt];
        lv += __shfl_xor(lv, 16);
        lv += __shfl_xor(lv, 32);           // every lane: full sum for q=l16
        #pragma unroll
        for (int r = 0; r < 4; ++r)
            linv[mt][r] = 1.0f / __shfl(lv, quad*4 + r);
    }

    // ---- store: out = relu(acc * linv) — no epilogue matmul needed ----
    float* obase = out + (size_t)bb * (NNODE * XROW) + tt * ND;
    #pragma unroll
    for (int mt = 0; mt < 2; ++mt)
        #pragma unroll
        for (int dt = 0; dt < 4; ++dt)
            #pragma unroll
            for (int r = 0; r < 4; ++r) {
                float v = acc[mt][dt][r] * linv[mt][r];
                obase[(size_t)(row0 + wave*32 + mt*16 + quad*4 + r) * XROW + dt*16 + l16]
                    = v > 0.f ? v : 0.f;
            }
}

// ---------------------------------------------------------------------------
// Fallback: verified R5 kernel (used only if workspace is too small).
// ---------------------------------------------------------------------------
__global__ void __launch_bounds__(256, 2)
spattn_fb(const float* __restrict__ x, const float* __restrict__ adj,
          const float* __restrict__ theta, float* __restrict__ out)
{
    __shared__ __align__(16) char smem[SMEM_FB];
    __bf16* Khi = (__bf16*)(smem + OFF_KHI);
    __bf16* Klo = (__bf16*)(smem + OFF_KLO);
    __bf16* Vhi = (__bf16*)(smem + OFF_VHI);
    __bf16* Vlo = (__bf16*)(smem + OFF_VLO);
    float*  Pm  = (float*)(smem + OFF_P);

    const int tid  = threadIdx.x;
    const int wave = tid >> 6;
    const int lane = tid & 63;
    const int l16  = lane & 15;
    const int quad = lane >> 4;

    const int bx   = blockIdx.x;
    const int g    = bx >> 3;
    const int rblk = bx & 7;
    const int bb   = g / NT;
    const int tt   = g - bb * NT;
    const int row0 = rblk * 128;

    const float* xbase = x + (size_t)bb * (NNODE * XROW) + tt * ND;

    bf16x8 qhi[2][2], qlo[2][2];
    #pragma unroll
    for (int mt = 0; mt < 2; ++mt) {
        const float* qsrc = xbase + (size_t)(row0 + wave*32 + mt*16 + l16) * XROW;
        #pragma unroll
        for (int ks = 0; ks < 2; ++ks) {
            floatx4 f0 = *(const floatx4*)(qsrc + ks*32 + quad*8);
            floatx4 f1 = *(const floatx4*)(qsrc + ks*32 + quad*8 + 4);
            #pragma unroll
            for (int i = 0; i < 4; ++i) {
                bfpair p0 = split1(f0[i]*QSCALE);
                qhi[mt][ks][i]   = p0.h; qlo[mt][ks][i]   = p0.l;
                bfpair p1 = split1(f1[i]*QSCALE);
                qhi[mt][ks][4+i] = p1.h; qlo[mt][ks][4+i] = p1.l;
            }
        }
    }

    const floatx4 vzero = {0.f, 0.f, 0.f, 0.f};
    floatx4 acc[2][4];
    #pragma unroll
    for (int mt = 0; mt < 2; ++mt)
        #pragma unroll
        for (int dt = 0; dt < 4; ++dt)
            acc[mt][dt] = vzero;
    float lpart[2][4] = {{0.f,0.f,0.f,0.f},{0.f,0.f,0.f,0.f}};

    const int skey = tid >> 3;
    const int sd0  = (tid & 7) * 8;
    const int svd  = tid >> 2;
    const int svk0 = (tid & 3) * 8;
    floatx4 kf0, kf1;
    float vf[8];

    {
        const float* ksrc = xbase + (size_t)skey * XROW + sd0;
        kf0 = *(const floatx4*)ksrc;
        kf1 = *(const floatx4*)(ksrc + 4);
        const float* vsrc = xbase + (size_t)svk0 * XROW + svd;
        #pragma unroll
        for (int i = 0; i < 8; ++i) vf[i] = vsrc[i * XROW];
    }

    for (int ct = 0; ct < 32; ++ct) {
        const int key0 = ct * 32;
        __syncthreads();
        {
            bf16x8 h, l;
            #pragma unroll
            for (int i = 0; i < 4; ++i) {
                bfpair p0 = split1(kf0[i]); h[i]   = p0.h; l[i]   = p0.l;
                bfpair p1 = split1(kf1[i]); h[4+i] = p1.h; l[4+i] = p1.l;
            }
            *(bf16x8*)(Khi + skey*KSTRIDE + sd0) = h;
            *(bf16x8*)(Klo + skey*KSTRIDE + sd0) = l;
            bf16x8 vh, vl;
            #pragma unroll
            for (int i = 0; i < 8; ++i) {
                bfpair p = split1(vf[i]); vh[i] = p.h; vl[i] = p.l;
            }
            *(bf16x8*)(Vhi + svd*VSTRIDE + svk0) = vh;
            *(bf16x8*)(Vlo + svd*VSTRIDE + svk0) = vl;
        }
        __syncthreads();
        if (ct < 31) {
            const int nk = key0 + 32;
            const float* ksrc = xbase + (size_t)(nk + skey) * XROW + sd0;
            kf0 = *(const floatx4*)ksrc;
            kf1 = *(const floatx4*)(ksrc + 4);
            const float* vsrc = xbase + (size_t)(nk + svk0) * XROW + svd;
            #pragma unroll
            for (int i = 0; i < 8; ++i) vf[i] = vsrc[i * XROW];
        }
        float av[2][2][4];
        #pragma unroll
        for (int mt = 0; mt < 2; ++mt)
            #pragma unroll
            for (int nt = 0; nt < 2; ++nt)
                #pragma unroll
                for (int r = 0; r < 4; ++r)
                    av[mt][nt][r] = adj[(size_t)(row0 + wave*32 + mt*16 + quad*4 + r) * NNODE
                                        + key0 + nt*16 + l16];

        floatx4 S[2][2] = {{vzero, vzero}, {vzero, vzero}};
        #pragma unroll
        for (int ks = 0; ks < 2; ++ks) {
            #pragma unroll
            for (int nt = 0; nt < 2; ++nt) {
                bf16x8 bh = *(const bf16x8*)(Khi + (nt*16 + l16)*KSTRIDE + ks*32 + quad*8);
                bf16x8 bl = *(const bf16x8*)(Klo + (nt*16 + l16)*KSTRIDE + ks*32 + quad*8);
                #pragma unroll
                for (int mt = 0; mt < 2; ++mt) {
                    S[mt][nt] = MFMA(qhi[mt][ks], bh, S[mt][nt]);
                    S[mt][nt] = MFMA(qlo[mt][ks], bh, S[mt][nt]);
                    S[mt][nt] = MFMA(qhi[mt][ks], bl, S[mt][nt]);
                }
            }
        }
        #pragma unroll
        for (int mt = 0; mt < 2; ++mt)
            #pragma unroll
            for (int nt = 0; nt < 2; ++nt)
                #pragma unroll
                for (int r = 0; r < 4; ++r) {
                    float w = __builtin_amdgcn_exp2f(S[mt][nt][r]);
                    lpart[mt][r] += w;
                    Pm[(wave*32 + mt*16 + quad*4 + r)*PSTRIDE + nt*16 + l16] = av[mt][nt][r] * w;
                }
        bf16x8 pah[2], pal[2];
        #pragma unroll
        for (int mt = 0; mt < 2; ++mt) {
            const float* pp = Pm + (wave*32 + mt*16 + l16)*PSTRIDE + quad*8;
            floatx4 p0 = *(const floatx4*)pp;
            floatx4 p1 = *(const floatx4*)(pp + 4);
            #pragma unroll
            for (int i = 0; i < 4; ++i) {
                bfpair q0 = split1(p0[i]); pah[mt][i]   = q0.h; pal[mt][i]   = q0.l;
                bfpair q1 = split1(p1[i]); pah[mt][4+i] = q1.h; pal[mt][4+i] = q1.l;
            }
        }
        #pragma unroll
        for (int dt = 0; dt < 4; ++dt) {
            bf16x8 vh = *(const bf16x8*)(Vhi + (dt*16 + l16)*VSTRIDE + quad*8);
            bf16x8 vl = *(const bf16x8*)(Vlo + (dt*16 + l16)*VSTRIDE + quad*8);
            #pragma unroll
            for (int mt = 0; mt < 2; ++mt) {
                acc[mt][dt] = MFMA(pah[mt], vh, acc[mt][dt]);
                acc[mt][dt] = MFMA(pal[mt], vh, acc[mt][dt]);
                acc[mt][dt] = MFMA(pah[mt], vl, acc[mt][dt]);
            }
        }
    }

    float linv[2][4];
    #pragma unroll
    for (int mt = 0; mt < 2; ++mt)
        #pragma unroll
        for (int r = 0; r < 4; ++r) {
            float lv = lpart[mt][r];
            lv += __shfl_xor(lv, 1);
            lv += __shfl_xor(lv, 2);
            lv += __shfl_xor(lv, 4);
            lv += __shfl_xor(lv, 8);
            linv[mt][r] = 1.0f / lv;
        }

    __syncthreads();
    float* AG = (float*)smem;
    #pragma unroll
    for (int mt = 0; mt < 2; ++mt)
        #pragma unroll
        for (int dt = 0; dt < 4; ++dt)
            #pragma unroll
            for (int r = 0; r < 4; ++r)
                AG[(wave*32 + mt*16 + quad*4 + r)*AGSTRIDE + dt*16 + l16]
                    = acc[mt][dt][r] * linv[mt][r];

    bf16x8 th[4][2], tl[4][2];
    #pragma unroll
    for (int ot = 0; ot < 4; ++ot)
        #pragma unroll
        for (int ks = 0; ks < 2; ++ks)
            #pragma unroll
            for (int j = 0; j < 8; ++j) {
                float tv = theta[(ks*32 + quad*8 + j)*ND + ot*16 + l16];
                bfpair p = split1(tv);
                th[ot][ks][j] = p.h; tl[ot][ks][j] = p.l;
            }

    floatx4 oacc[2][4];
    #pragma unroll
    for (int mt = 0; mt < 2; ++mt)
        #pragma unroll
        for (int ot = 0; ot < 4; ++ot)
            oacc[mt][ot] = vzero;
    __syncthreads();
    #pragma unroll
    for (int ks = 0; ks < 2; ++ks) {
        bf16x8 ah[2], al[2];
        #pragma unroll
        for (int mt = 0; mt < 2; ++mt) {
            const float* ap = AG + (wave*32 + mt*16 + l16)*AGSTRIDE + ks*32 + quad*8;
            floatx4 a0 = *(const floatx4*)ap;
            floatx4 a1 = *(const floatx4*)(ap + 4);
            #pragma unroll
            for (int i = 0; i < 4; ++i) {
                bfpair q0 = split1(a0[i]); ah[mt][i]   = q0.h; al[mt][i]   = q0.l;
                bfpair q1 = split1(a1[i]); ah[mt][4+i] = q1.h; al[mt][4+i] = q1.l;
            }
        }
        #pragma unroll
        for (int ot = 0; ot < 4; ++ot)
            #pragma unroll
            for (int mt = 0; mt < 2; ++mt) {
                oacc[mt][ot] = MFMA(ah[mt], th[ot][ks], oacc[mt][ot]);
                oacc[mt][ot] = MFMA(al[mt], th[ot][ks], oacc[mt][ot]);
                oacc[mt][ot] = MFMA(ah[mt], tl[ot][ks], oacc[mt][ot]);
            }
    }

    float* obase = out + (size_t)bb * (NNODE * XROW) + tt * ND;
    #pragma unroll
    for (int mt = 0; mt < 2; ++mt)
        #pragma unroll
        for (int ot = 0; ot < 4; ++ot)
            #pragma unroll
            for (int r = 0; r < 4; ++r) {
                float v = oacc[mt][ot][r];
                obase[(size_t)(row0 + wave*32 + mt*16 + quad*4 + r) * XROW + ot*16 + l16]
                    = v > 0.f ? v : 0.f;
            }
}

extern "C" void kernel_launch(void* const* d_in, const int* in_sizes, int n_in,
                              void* d_out, int out_size, void* d_ws, size_t ws_size,
                              hipStream_t stream) {
    (void)in_sizes; (void)n_in; (void)out_size;
    const float* x     = (const float*)d_in[0];
    const float* adj   = (const float*)d_in[1];
    const float* theta = (const float*)d_in[2];
    float* out = (float*)d_out;
    if (d_ws != nullptr && ws_size >= WS_BYTES) {
        __bf16* ws = (__bf16*)d_ws;
        presplit<<<dim3(1536), dim3(256), 0, stream>>>(x, theta, ws);
        spattn11<<<dim3(768), dim3(256), 0, stream>>>(ws, adj, out);
    } else {
        spattn_fb<<<dim3(768), dim3(256), 0, stream>>>(x, adj, theta, out);
    }
}

// Round 12
// 168.266 us; speedup vs baseline: 1.1345x; 1.1345x over previous
//
#include <hip/hip_runtime.h>

// PositionWiseSpatialAttention — fused flash-style kernel, MI355X gfx950.
//
// R17 = R15 (R13 + setprio, 92.0us) with staging converted to async
// global_load_lds (width 16). R14/R16 proved any reg-lifetime extension
// spills; global_load_lds goes the OTHER way: no VGPR round-trip, no
// ds_write ops (4 wave-ops/iter off the ~55%-busy LDS pipe), async until
// the barrier's vmcnt(0) drain (~550 cyc of cover, data L2-hot).
// Constraint (m104/m173): LDS dest = wave-uniform base + lane*16, linear.
// So pads are dropped (K rows 128B, W macro-rows 128B) and bank conflicts
// are prevented per rule #21: linear dest + INVERSE-swizzled global source
// + matching XOR on the read:
//   K: 16B-chunk' = chunk ^ (row&7)   within each 128B row   -> reads 2-way
//   W: 16B-chunk' = chunk ^ (macro&7) within each 128B macro -> reads 2-way
// (write side is stride-1, conflict-free). Stored data is bit-identical to
// R15 -> absmax must be exactly 3.051758e-05 (built-in correctness check).
// PRIMARY CHECKS: WRITE_SIZE ~24.6MB (no spill), VGPR ~64-72.

#define NB    8
#define NT    12
#define NNODE 1024
#define ND    64
#define XROW  768   /* NT*ND: stride between consecutive n for fixed (b,t) */
#define NG    96    /* NB*NT */

typedef __bf16 bf16x8 __attribute__((ext_vector_type(8)));
typedef __bf16 bf16x4 __attribute__((ext_vector_type(4)));
typedef float  floatx4 __attribute__((ext_vector_type(4)));

#define MFMA(a,b,c) __builtin_amdgcn_mfma_f32_16x16x32_bf16((a),(b),(c),0,0,0)

#define QSCALE 0.18033688011112042f   /* 0.125 * log2(e) */

// New per-buffer LDS layout (bytes): 4 linear 4KB arrays, swizzled content.
#define OKH 0
#define OKL 4096
#define OWH 8192
#define OWL 12288
#define BUF2 16384
#define SMEM12 (2 * BUF2)                 /* 32768 */
// fallback (R5) LDS map
#define KSTRIDE 72
#define VSTRIDE 40
#define PSTRIDE 36
#define AGSTRIDE 68
#define OFF_KHI 0
#define OFF_KLO 4608
#define OFF_VHI 9216
#define OFF_VLO 14336
#define OFF_P   19456
#define SMEM_FB (19456 + 128*PSTRIDE*4)   /* 37888 */

// workspace element offsets (__bf16 units)
#define WXHI  0          /* [96][1024][64] row-major hi           */
#define WXLO  6291456
#define WVPHI 12582912   /* [96][64 o][1024] W^T permuted hi       */
#define WVPLO 18874368
#define WS_BYTES 50348032ULL

struct bfpair { __bf16 h, l; };

// error-compensated split: hi = RNE(f) via native fptrunc, lo = RNE(f - hi).
__device__ __forceinline__ bfpair split1(float f) {
    bfpair r;
    __bf16 hb = (__bf16)f;
    float hf = __builtin_bit_cast(float,
                   (unsigned)__builtin_bit_cast(unsigned short, hb) << 16);
    r.h = hb;
    r.l = (__bf16)(f - hf);
    return r;
}

// async global->LDS, 16B per lane; dest = wave-uniform base + lane*16.
__device__ __forceinline__ void gld16(const __bf16* g, char* l) {
    __builtin_amdgcn_global_load_lds(
        (const __attribute__((address_space(1))) void*)g,
        (__attribute__((address_space(3))) void*)l, 16, 0, 0);
}

// ---------------------------------------------------------------------------
// presplit: grid 1536 (96 g x 16 n-blocks), 256 threads. (R13, verified)
// Phase A: x tile -> T (LDS) + row-major split -> Xhi/Xlo.
// Phase B: W = T · Θ via 3-term split-bf16 MFMA -> Wt (LDS, f32).
// Phase C: transposed+PERMUTED split of Wt -> WVPhi/lo.
//   Position c in each 32-key tile holds key k(c)=((c&7)>>2)*16+(c>>3)*4+(c&3).
// ---------------------------------------------------------------------------
__global__ void __launch_bounds__(256)
presplit(const float* __restrict__ x, const float* __restrict__ theta,
         __bf16* __restrict__ ws)
{
    __shared__ __align__(16) float T[64 * 68];
    __shared__ __align__(16) float Wt[64 * 68];
    const int tid  = threadIdx.x;
    const int lane = tid & 63;
    const int wave = tid >> 6;
    const int l16  = lane & 15;
    const int quad = lane >> 4;
    const int bx   = blockIdx.x;
    const int g    = bx >> 4;
    const int nblk = bx & 15;
    const int bb   = g / NT;
    const int tt   = g - bb * NT;
    const int n0   = nblk * 64;

    __bf16* Xhi  = ws + WXHI  + (size_t)g * 65536;
    __bf16* Xlo  = ws + WXLO  + (size_t)g * 65536;
    __bf16* WPhi = ws + WVPHI + (size_t)g * 65536;
    __bf16* WPlo = ws + WVPLO + (size_t)g * 65536;
    const float* xg = x + (size_t)bb * (NNODE * XROW) + (size_t)tt * ND;

    // ---- Phase A: 64x64 fp32 tile -> T + row-major split ----
    #pragma unroll
    for (int i = 0; i < 4; ++i) {
        int chunk = i * 256 + tid;        // 0..1023
        int n  = chunk >> 4;              // 0..63
        int c4 = (chunk & 15) * 4;        // 0..60
        floatx4 f = *(const floatx4*)(xg + (size_t)(n0 + n) * XROW + c4);
        *(floatx4*)(T + n * 68 + c4) = f;
        bf16x4 h, l;
        #pragma unroll
        for (int j = 0; j < 4; ++j) {
            bfpair p = split1(f[j]); h[j] = p.h; l[j] = p.l;
        }
        *(bf16x4*)(Xhi + (size_t)(n0 + n) * 64 + c4) = h;
        *(bf16x4*)(Xlo + (size_t)(n0 + n) * 64 + c4) = l;
    }
    __syncthreads();

    // ---- Phase B: W = T · Θ (3-term split-bf16 MFMA), wave owns 16 keys ----
    {
        bf16x8 tah[2], tal[2];
        #pragma unroll
        for (int ks = 0; ks < 2; ++ks)
            #pragma unroll
            for (int j = 0; j < 8; ++j) {
                bfpair p = split1(T[(wave*16 + l16)*68 + ks*32 + quad*8 + j]);
                tah[ks][j] = p.h; tal[ks][j] = p.l;
            }
        const floatx4 vz = {0.f, 0.f, 0.f, 0.f};
        #pragma unroll
        for (int ot = 0; ot < 4; ++ot) {
            bf16x8 thb[2], tlb[2];
            #pragma unroll
            for (int ks = 0; ks < 2; ++ks)
                #pragma unroll
                for (int j = 0; j < 8; ++j) {
                    bfpair p = split1(theta[(size_t)(ks*32 + quad*8 + j) * ND
                                            + ot*16 + l16]);
                    thb[ks][j] = p.h; tlb[ks][j] = p.l;
                }
            floatx4 Wc = vz;
            #pragma unroll
            for (int ks = 0; ks < 2; ++ks) {
                Wc = MFMA(tah[ks], thb[ks], Wc);
                Wc = MFMA(tal[ks], thb[ks], Wc);
                Wc = MFMA(tah[ks], tlb[ks], Wc);
            }
            #pragma unroll
            for (int r = 0; r < 4; ++r)
                Wt[(wave*16 + quad*4 + r)*68 + ot*16 + l16] = Wc[r];
        }
    }
    __syncthreads();

    // ---- Phase C: transposed + permuted split of Wt (verified code) ----
    {
        const int o  = tid >> 2;          // 0..63
        const int nc = (tid & 3) * 16;    // 0..48 (dst positions nc..nc+15)
        const int tb = nc & 32;           // 32-key tile base within the 64-blk
        bf16x8 h0, l0, h1, l1;
        #pragma unroll
        for (int j = 0; j < 8; ++j) {
            int c0 = (nc & 31) + j;       // dst position in tile
            int k0 = ((c0 & 7) >> 2) * 16 + (c0 >> 3) * 4 + (c0 & 3);
            bfpair p = split1(Wt[(tb + k0) * 68 + o]);
            h0[j] = p.h; l0[j] = p.l;
            int c1 = (nc & 31) + 8 + j;
            int k1 = ((c1 & 7) >> 2) * 16 + (c1 >> 3) * 4 + (c1 & 3);
            bfpair q = split1(Wt[(tb + k1) * 68 + o]);
            h1[j] = q.h; l1[j] = q.l;
        }
        __bf16* dsth = WPhi + (size_t)o * NNODE + n0 + nc;
        __bf16* dstl = WPlo + (size_t)o * NNODE + n0 + nc;
        *(bf16x8*)dsth = h0; *(bf16x8*)(dsth + 8) = h1;
        *(bf16x8*)dstl = l0; *(bf16x8*)(dstl + 8) = l1;
    }
}

// ---------------------------------------------------------------------------
// spattn12: grid 768 (bx = rblk*96 + g), 256 threads, 4 waves x 32 rows.
// R15 loop; staging via async global_load_lds with source/read swizzle.
// ---------------------------------------------------------------------------
__global__ void __launch_bounds__(256, 3)
spattn12(const __bf16* __restrict__ ws, const float* __restrict__ adj,
         float* __restrict__ out)
{
    __shared__ __align__(16) char smem[SMEM12];

    const int tid  = threadIdx.x;
    const int wave = tid >> 6;          // 0..3, owns rows wave*32..+31
    const int lane = tid & 63;
    const int l16  = lane & 15;
    const int quad = lane >> 4;

    // bx = rblk*96 + g: all 8 row-blocks of a g share bx%8 -> same XCD.
    const int bx   = blockIdx.x;
    const int g    = bx % NG;           // 0..95
    const int rblk = bx / NG;           // 0..7
    const int bb   = g / NT;
    const int tt   = g - bb * NT;
    const int row0 = rblk * 128;

    const __bf16* xh  = ws + WXHI  + (size_t)g * 65536;
    const __bf16* xl  = ws + WXLO  + (size_t)g * 65536;
    const __bf16* wph = ws + WVPHI + (size_t)g * 65536;
    const __bf16* wpl = ws + WVPLO + (size_t)g * 65536;

    // staging source maps (per-lane, tile-invariant).
    // K: lane covers (row = 8*wave + lane>>3, dest chunk lane&7); the data
    //    placed there is source chunk (lane&7)^(row&7), row&7 = lane>>3.
    const int kc   = (lane & 7) ^ (lane >> 3);       // K/W source chunk
    const int krow = (wave << 3) + (lane >> 3);      // K row (0..31)
    // W: macro = 8*wave + lane>>3 covers o = 2*macro + (kc>>2), key (kc&3)*8
    const int wo   = ((wave << 3) + (lane >> 3)) * 2 + ((kc & 4) >> 2);
    const int wko  = (kc & 3) * 8;

    // ---- Q fragments b128 from row-major split arrays (B operand) ----
    bf16x8 qhi[2][2], qlo[2][2];
    #pragma unroll
    for (int mt = 0; mt < 2; ++mt) {
        const __bf16* q0 = xh + (size_t)(row0 + wave*32 + mt*16 + l16) * 64 + quad*8;
        const __bf16* q1 = xl + (size_t)(row0 + wave*32 + mt*16 + l16) * 64 + quad*8;
        #pragma unroll
        for (int ks = 0; ks < 2; ++ks) {
            qhi[mt][ks] = *(const bf16x8*)(q0 + ks*32);
            qlo[mt][ks] = *(const bf16x8*)(q1 + ks*32);
        }
    }

    const floatx4 vzero = {0.f, 0.f, 0.f, 0.f};
    floatx4 acc[2][4];
    #pragma unroll
    for (int mt = 0; mt < 2; ++mt)
        #pragma unroll
        for (int dt = 0; dt < 4; ++dt)
            acc[mt][dt] = vzero;
    float lpart[2] = {0.f, 0.f};        // per-lane partial: q = l16 (per mt)

    // prologue: async-stage tile 0 into buffer 0 (drained by first barrier)
    {
        char* b0 = smem;
        gld16(xh  + (size_t)krow * 64 + kc*8,          b0 + OKH + wave*1024);
        gld16(xl  + (size_t)krow * 64 + kc*8,          b0 + OKL + wave*1024);
        gld16(wph + (size_t)wo * NNODE + wko,          b0 + OWH + wave*1024);
        gld16(wpl + (size_t)wo * NNODE + wko,          b0 + OWL + wave*1024);
    }

    int cur = 0;
    for (int ct = 0; ct < 32; ++ct) {
        const int key0 = ct * 32;
        __syncthreads();   // drains in-flight gloads (tile ct now visible);
                           // all waves done reading buf[cur^1]
        if (ct < 31) {     // async-stage tile ct+1 into the dead buffer
            const int nk = key0 + 32;
            char* wb = smem + (cur ^ 1) * BUF2;
            gld16(xh  + (size_t)(nk + krow) * 64 + kc*8, wb + OKH + wave*1024);
            gld16(xl  + (size_t)(nk + krow) * 64 + kc*8, wb + OKL + wave*1024);
            gld16(wph + (size_t)wo * NNODE + nk + wko,   wb + OWH + wave*1024);
            gld16(wpl + (size_t)wo * NNODE + nk + wko,   wb + OWL + wave*1024);
        }
        // adj: float4 loads; lane l16 = q-row, quad*4+r = key within nt-tile
        floatx4 av[2][2];
        #pragma unroll
        for (int mt = 0; mt < 2; ++mt)
            #pragma unroll
            for (int nt = 0; nt < 2; ++nt)
                av[mt][nt] = *(const floatx4*)(adj
                    + (size_t)(row0 + wave*32 + mt*16 + l16) * NNODE
                    + key0 + nt*16 + quad*4);

        char* rb = smem + cur * BUF2;
        __bf16* Khi = (__bf16*)(rb + OKH);
        __bf16* Klo = (__bf16*)(rb + OKL);
        __bf16* Whi = (__bf16*)(rb + OWH);
        __bf16* Wlo = (__bf16*)(rb + OWL);

        // ---- S^T = K Q^T (swapped operands; 3-term split bf16) ----
        // Output: col = q = l16, row = key = nt*16 + quad*4 + r.
        // K read swizzle: chunk (ks*4+quad) stored at chunk^(row&7).
        floatx4 S[2][2] = {{vzero, vzero}, {vzero, vzero}};   // [mt][nt]
        __builtin_amdgcn_s_setprio(1);
        #pragma unroll
        for (int ks = 0; ks < 2; ++ks) {
            #pragma unroll
            for (int nt = 0; nt < 2; ++nt) {
                const int kch = (((ks*4 + quad) ^ (l16 & 7))) * 8;
                bf16x8 ah = *(const bf16x8*)(Khi + (nt*16 + l16)*64 + kch);
                bf16x8 al = *(const bf16x8*)(Klo + (nt*16 + l16)*64 + kch);
                #pragma unroll
                for (int mt = 0; mt < 2; ++mt) {
                    S[mt][nt] = MFMA(ah, qhi[mt][ks], S[mt][nt]);
                    S[mt][nt] = MFMA(ah, qlo[mt][ks], S[mt][nt]);
                    S[mt][nt] = MFMA(al, qhi[mt][ks], S[mt][nt]);
                }
            }
        }
        __builtin_amdgcn_s_setprio(0);

        // ---- exp2 + adj-mask + split, ALL in registers ----
        bf16x8 pah[2], pal[2];
        #pragma unroll
        for (int mt = 0; mt < 2; ++mt)
            #pragma unroll
            for (int nt = 0; nt < 2; ++nt)
                #pragma unroll
                for (int r = 0; r < 4; ++r) {
                    float w = __builtin_amdgcn_exp2f(S[mt][nt][r] * QSCALE);
                    lpart[mt] += w;
                    bfpair pp = split1(av[mt][nt][r] * w);
                    pah[mt][nt*4 + r] = pp.h;
                    pal[mt][nt*4 + r] = pp.l;
                }

        // ---- acc += P . W (3-term split) ----
        // W read swizzle: macro m = dt*8 + (l16>>1); source chunk
        // c = (l16&1)*4 + quad stored at c^(m&7), m&7 = (l16>>1)&7.
        __builtin_amdgcn_s_setprio(1);
        #pragma unroll
        for (int dt = 0; dt < 4; ++dt) {
            const int wmr = dt*8 + (l16 >> 1);
            const int wch = ((((l16 & 1)*4 + quad) ^ ((l16 >> 1) & 7))) * 8;
            bf16x8 wvh = *(const bf16x8*)(Whi + wmr*64 + wch);
            bf16x8 wvl = *(const bf16x8*)(Wlo + wmr*64 + wch);
            #pragma unroll
            for (int mt = 0; mt < 2; ++mt) {
                acc[mt][dt] = MFMA(pah[mt], wvh, acc[mt][dt]);
                acc[mt][dt] = MFMA(pal[mt], wvh, acc[mt][dt]);
                acc[mt][dt] = MFMA(pah[mt], wvl, acc[mt][dt]);
            }
        }
        __builtin_amdgcn_s_setprio(0);
        cur ^= 1;
    }

    // ---- denominator: reduce across quads (each lane has q = l16) ----
    float linv[2][4];
    #pragma unroll
    for (int mt = 0; mt < 2; ++mt) {
        float lv = lpart[mt];
        lv += __shfl_xor(lv, 16);
        lv += __shfl_xor(lv, 32);           // every lane: full sum for q=l16
        #pragma unroll
        for (int r = 0; r < 4; ++r)
            linv[mt][r] = 1.0f / __shfl(lv, quad*4 + r);
    }

    // ---- store: out = relu(acc * linv) — no epilogue matmul needed ----
    float* obase = out + (size_t)bb * (NNODE * XROW) + tt * ND;
    #pragma unroll
    for (int mt = 0; mt < 2; ++mt)
        #pragma unroll
        for (int dt = 0; dt < 4; ++dt)
            #pragma unroll
            for (int r = 0; r < 4; ++r) {
                float v = acc[mt][dt][r] * linv[mt][r];
                obase[(size_t)(row0 + wave*32 + mt*16 + quad*4 + r) * XROW + dt*16 + l16]
                    = v > 0.f ? v : 0.f;
            }
}

// ---------------------------------------------------------------------------
// Fallback: verified R5 kernel (used only if workspace is too small).
// ---------------------------------------------------------------------------
__global__ void __launch_bounds__(256, 2)
spattn_fb(const float* __restrict__ x, const float* __restrict__ adj,
          const float* __restrict__ theta, float* __restrict__ out)
{
    __shared__ __align__(16) char smem[SMEM_FB];
    __bf16* Khi = (__bf16*)(smem + OFF_KHI);
    __bf16* Klo = (__bf16*)(smem + OFF_KLO);
    __bf16* Vhi = (__bf16*)(smem + OFF_VHI);
    __bf16* Vlo = (__bf16*)(smem + OFF_VLO);
    float*  Pm  = (float*)(smem + OFF_P);

    const int tid  = threadIdx.x;
    const int wave = tid >> 6;
    const int lane = tid & 63;
    const int l16  = lane & 15;
    const int quad = lane >> 4;

    const int bx   = blockIdx.x;
    const int g    = bx >> 3;
    const int rblk = bx & 7;
    const int bb   = g / NT;
    const int tt   = g - bb * NT;
    const int row0 = rblk * 128;

    const float* xbase = x + (size_t)bb * (NNODE * XROW) + tt * ND;

    bf16x8 qhi[2][2], qlo[2][2];
    #pragma unroll
    for (int mt = 0; mt < 2; ++mt) {
        const float* qsrc = xbase + (size_t)(row0 + wave*32 + mt*16 + l16) * XROW;
        #pragma unroll
        for (int ks = 0; ks < 2; ++ks) {
            floatx4 f0 = *(const floatx4*)(qsrc + ks*32 + quad*8);
            floatx4 f1 = *(const floatx4*)(qsrc + ks*32 + quad*8 + 4);
            #pragma unroll
            for (int i = 0; i < 4; ++i) {
                bfpair p0 = split1(f0[i]*QSCALE);
                qhi[mt][ks][i]   = p0.h; qlo[mt][ks][i]   = p0.l;
                bfpair p1 = split1(f1[i]*QSCALE);
                qhi[mt][ks][4+i] = p1.h; qlo[mt][ks][4+i] = p1.l;
            }
        }
    }

    const floatx4 vzero = {0.f, 0.f, 0.f, 0.f};
    floatx4 acc[2][4];
    #pragma unroll
    for (int mt = 0; mt < 2; ++mt)
        #pragma unroll
        for (int dt = 0; dt < 4; ++dt)
            acc[mt][dt] = vzero;
    float lpart[2][4] = {{0.f,0.f,0.f,0.f},{0.f,0.f,0.f,0.f}};

    const int skey = tid >> 3;
    const int sd0  = (tid & 7) * 8;
    const int svd  = tid >> 2;
    const int svk0 = (tid & 3) * 8;
    floatx4 kf0, kf1;
    float vf[8];

    {
        const float* ksrc = xbase + (size_t)skey * XROW + sd0;
        kf0 = *(const floatx4*)ksrc;
        kf1 = *(const floatx4*)(ksrc + 4);
        const float* vsrc = xbase + (size_t)svk0 * XROW + svd;
        #pragma unroll
        for (int i = 0; i < 8; ++i) vf[i] = vsrc[i * XROW];
    }

    for (int ct = 0; ct < 32; ++ct) {
        const int key0 = ct * 32;
        __syncthreads();
        {
            bf16x8 h, l;
            #pragma unroll
            for (int i = 0; i < 4; ++i) {
                bfpair p0 = split1(kf0[i]); h[i]   = p0.h; l[i]   = p0.l;
                bfpair p1 = split1(kf1[i]); h[4+i] = p1.h; l[4+i] = p1.l;
            }
            *(bf16x8*)(Khi + skey*KSTRIDE + sd0) = h;
            *(bf16x8*)(Klo + skey*KSTRIDE + sd0) = l;
            bf16x8 vh, vl;
            #pragma unroll
            for (int i = 0; i < 8; ++i) {
                bfpair p = split1(vf[i]); vh[i] = p.h; vl[i] = p.l;
            }
            *(bf16x8*)(Vhi + svd*VSTRIDE + svk0) = vh;
            *(bf16x8*)(Vlo + svd*VSTRIDE + svk0) = vl;
        }
        __syncthreads();
        if (ct < 31) {
            const int nk = key0 + 32;
            const float* ksrc = xbase + (size_t)(nk + skey) * XROW + sd0;
            kf0 = *(const floatx4*)ksrc;
            kf1 = *(const floatx4*)(ksrc + 4);
            const float* vsrc = xbase + (size_t)(nk + svk0) * XROW + svd;
            #pragma unroll
            for (int i = 0; i < 8; ++i) vf[i] = vsrc[i * XROW];
        }
        float av[2][2][4];
        #pragma unroll
        for (int mt = 0; mt < 2; ++mt)
            #pragma unroll
            for (int nt = 0; nt < 2; ++nt)
                #pragma unroll
                for (int r = 0; r < 4; ++r)
                    av[mt][nt][r] = adj[(size_t)(row0 + wave*32 + mt*16 + quad*4 + r) * NNODE
                                        + key0 + nt*16 + l16];

        floatx4 S[2][2] = {{vzero, vzero}, {vzero, vzero}};
        #pragma unroll
        for (int ks = 0; ks < 2; ++ks) {
            #pragma unroll
            for (int nt = 0; nt < 2; ++nt) {
                bf16x8 bh = *(const bf16x8*)(Khi + (nt*16 + l16)*KSTRIDE + ks*32 + quad*8);
                bf16x8 bl = *(const bf16x8*)(Klo + (nt*16 + l16)*KSTRIDE + ks*32 + quad*8);
                #pragma unroll
                for (int mt = 0; mt < 2; ++mt) {
                    S[mt][nt] = MFMA(qhi[mt][ks], bh, S[mt][nt]);
                    S[mt][nt] = MFMA(qlo[mt][ks], bh, S[mt][nt]);
                    S[mt][nt] = MFMA(qhi[mt][ks], bl, S[mt][nt]);
                }
            }
        }
        #pragma unroll
        for (int mt = 0; mt < 2; ++mt)
            #pragma unroll
            for (int nt = 0; nt < 2; ++nt)
                #pragma unroll
                for (int r = 0; r < 4; ++r) {
                    float w = __builtin_amdgcn_exp2f(S[mt][nt][r]);
                    lpart[mt][r] += w;
                    Pm[(wave*32 + mt*16 + quad*4 + r)*PSTRIDE + nt*16 + l16] = av[mt][nt][r] * w;
                }
        bf16x8 pah[2], pal[2];
        #pragma unroll
        for (int mt = 0; mt < 2; ++mt) {
            const float* pp = Pm + (wave*32 + mt*16 + l16)*PSTRIDE + quad*8;
            floatx4 p0 = *(const floatx4*)pp;
            floatx4 p1 = *(const floatx4*)(pp + 4);
            #pragma unroll
            for (int i = 0; i < 4; ++i) {
                bfpair q0 = split1(p0[i]); pah[mt][i]   = q0.h; pal[mt][i]   = q0.l;
                bfpair q1 = split1(p1[i]); pah[mt][4+i] = q1.h; pal[mt][4+i] = q1.l;
            }
        }
        #pragma unroll
        for (int dt = 0; dt < 4; ++dt) {
            bf16x8 vh = *(const bf16x8*)(Vhi + (dt*16 + l16)*VSTRIDE + quad*8);
            bf16x8 vl = *(const bf16x8*)(Vlo + (dt*16 + l16)*VSTRIDE + quad*8);
            #pragma unroll
            for (int mt = 0; mt < 2; ++mt) {
                acc[mt][dt] = MFMA(pah[mt], vh, acc[mt][dt]);
                acc[mt][dt] = MFMA(pal[mt], vh, acc[mt][dt]);
                acc[mt][dt] = MFMA(pah[mt], vl, acc[mt][dt]);
            }
        }
    }

    float linv[2][4];
    #pragma unroll
    for (int mt = 0; mt < 2; ++mt)
        #pragma unroll
        for (int r = 0; r < 4; ++r) {
            float lv = lpart[mt][r];
            lv += __shfl_xor(lv, 1);
            lv += __shfl_xor(lv, 2);
            lv += __shfl_xor(lv, 4);
            lv += __shfl_xor(lv, 8);
            linv[mt][r] = 1.0f / lv;
        }

    __syncthreads();
    float* AG = (float*)smem;
    #pragma unroll
    for (int mt = 0; mt < 2; ++mt)
        #pragma unroll
        for (int dt = 0; dt < 4; ++dt)
            #pragma unroll
            for (int r = 0; r < 4; ++r)
                AG[(wave*32 + mt*16 + quad*4 + r)*AGSTRIDE + dt*16 + l16]
                    = acc[mt][dt][r] * linv[mt][r];

    bf16x8 th[4][2], tl[4][2];
    #pragma unroll
    for (int ot = 0; ot < 4; ++ot)
        #pragma unroll
        for (int ks = 0; ks < 2; ++ks)
            #pragma unroll
            for (int j = 0; j < 8; ++j) {
                float tv = theta[(ks*32 + quad*8 + j)*ND + ot*16 + l16];
                bfpair p = split1(tv);
                th[ot][ks][j] = p.h; tl[ot][ks][j] = p.l;
            }

    floatx4 oacc[2][4];
    #pragma unroll
    for (int mt = 0; mt < 2; ++mt)
        #pragma unroll
        for (int ot = 0; ot < 4; ++ot)
            oacc[mt][ot] = vzero;
    __syncthreads();
    #pragma unroll
    for (int ks = 0; ks < 2; ++ks) {
        bf16x8 ah[2], al[2];
        #pragma unroll
        for (int mt = 0; mt < 2; ++mt) {
            const float* ap = AG + (wave*32 + mt*16 + l16)*AGSTRIDE + ks*32 + quad*8;
            floatx4 a0 = *(const floatx4*)ap;
            floatx4 a1 = *(const floatx4*)(ap + 4);
            #pragma unroll
            for (int i = 0; i < 4; ++i) {
                bfpair q0 = split1(a0[i]); ah[mt][i]   = q0.h; al[mt][i]   = q0.l;
                bfpair q1 = split1(a1[i]); ah[mt][4+i] = q1.h; al[mt][4+i] = q1.l;
            }
        }
        #pragma unroll
        for (int ot = 0; ot < 4; ++ot)
            #pragma unroll
            for (int mt = 0; mt < 2; ++mt) {
                oacc[mt][ot] = MFMA(ah[mt], th[ot][ks], oacc[mt][ot]);
                oacc[mt][ot] = MFMA(al[mt], th[ot][ks], oacc[mt][ot]);
                oacc[mt][ot] = MFMA(ah[mt], tl[ot][ks], oacc[mt][ot]);
            }
    }

    float* obase = out + (size_t)bb * (NNODE * XROW) + tt * ND;
    #pragma unroll
    for (int mt = 0; mt < 2; ++mt)
        #pragma unroll
        for (int ot = 0; ot < 4; ++ot)
            #pragma unroll
            for (int r = 0; r < 4; ++r) {
                float v = oacc[mt][ot][r];
                obase[(size_t)(row0 + wave*32 + mt*16 + quad*4 + r) * XROW + ot*16 + l16]
                    = v > 0.f ? v : 0.f;
            }
}

extern "C" void kernel_launch(void* const* d_in, const int* in_sizes, int n_in,
                              void* d_out, int out_size, void* d_ws, size_t ws_size,
                              hipStream_t stream) {
    (void)in_sizes; (void)n_in; (void)out_size;
    const float* x     = (const float*)d_in[0];
    const float* adj   = (const float*)d_in[1];
    const float* theta = (const float*)d_in[2];
    float* out = (float*)d_out;
    if (d_ws != nullptr && ws_size >= WS_BYTES) {
        __bf16* ws = (__bf16*)d_ws;
        presplit<<<dim3(1536), dim3(256), 0, stream>>>(x, theta, ws);
        spattn12<<<dim3(768), dim3(256), 0, stream>>>(ws, adj, out);
    } else {
        spattn_fb<<<dim3(768), dim3(256), 0, stream>>>(x, adj, theta, out);
    }
}

// Round 13
// 167.216 us; speedup vs baseline: 1.1416x; 1.0063x over previous
//
#include <hip/hip_runtime.h>

// PositionWiseSpatialAttention — fused flash-style kernel, MI355X gfx950.
//
// R18 = R17 (gld_lds staging, 0 bank conflicts, 88.1us) + T15-style skewed
// pipeline: PW is delayed one tile so PW(ct-1) is independent of exp(ct) ->
// the compiler interleaves PW MFMAs with the exp/split VALU (the two pipes
// finally co-run within a wave; R17's chain was strictly serial).
//  - P carried in regs across the barrier (pah/pal_prev, +16 VGPR).
//  - 3 LDS buffers (48KB): buf b holds tile t=b mod 3; K-read at t, W-read
//    at t+1, rewritten by loads issued at t+2-top -> no WAR race with
//    1-ahead prefetch (checked: reads of b never overlap writes of b).
//  - launch_bounds(256,2): 256-reg allocator budget (R14/R16 spills were
//    under the (256,3)/170 budget); occupancy LDS-capped at 3 blocks/CU
//    (147KB) either way -> same 12 waves/CU as R17.
// Per-tile accumulation order unchanged -> absmax bit-identical 3.0518e-05.
// PRIMARY CHECKS: WRITE_SIZE ~24.6MB (no spill), conflicts stay 0.

#define NB    8
#define NT    12
#define NNODE 1024
#define ND    64
#define XROW  768   /* NT*ND: stride between consecutive n for fixed (b,t) */
#define NG    96    /* NB*NT */

typedef __bf16 bf16x8 __attribute__((ext_vector_type(8)));
typedef __bf16 bf16x4 __attribute__((ext_vector_type(4)));
typedef float  floatx4 __attribute__((ext_vector_type(4)));

#define MFMA(a,b,c) __builtin_amdgcn_mfma_f32_16x16x32_bf16((a),(b),(c),0,0,0)

#define QSCALE 0.18033688011112042f   /* 0.125 * log2(e) */

// Per-buffer LDS layout (bytes): 4 linear 4KB arrays, swizzled content.
#define OKH 0
#define OKL 4096
#define OWH 8192
#define OWL 12288
#define BUF2 16384
#define SMEM13 (3 * BUF2)                 /* 49152: triple buffer */
// fallback (R5) LDS map
#define KSTRIDE 72
#define VSTRIDE 40
#define PSTRIDE 36
#define AGSTRIDE 68
#define OFF_KHI 0
#define OFF_KLO 4608
#define OFF_VHI 9216
#define OFF_VLO 14336
#define OFF_P   19456
#define SMEM_FB (19456 + 128*PSTRIDE*4)   /* 37888 */

// workspace element offsets (__bf16 units)
#define WXHI  0          /* [96][1024][64] row-major hi           */
#define WXLO  6291456
#define WVPHI 12582912   /* [96][64 o][1024] W^T permuted hi       */
#define WVPLO 18874368
#define WS_BYTES 50348032ULL

struct bfpair { __bf16 h, l; };

// error-compensated split: hi = RNE(f) via native fptrunc, lo = RNE(f - hi).
__device__ __forceinline__ bfpair split1(float f) {
    bfpair r;
    __bf16 hb = (__bf16)f;
    float hf = __builtin_bit_cast(float,
                   (unsigned)__builtin_bit_cast(unsigned short, hb) << 16);
    r.h = hb;
    r.l = (__bf16)(f - hf);
    return r;
}

// async global->LDS, 16B per lane; dest = wave-uniform base + lane*16.
__device__ __forceinline__ void gld16(const __bf16* g, char* l) {
    __builtin_amdgcn_global_load_lds(
        (const __attribute__((address_space(1))) void*)g,
        (__attribute__((address_space(3))) void*)l, 16, 0, 0);
}

// ---------------------------------------------------------------------------
// presplit: grid 1536 (96 g x 16 n-blocks), 256 threads. (R13, verified)
// Phase A: x tile -> T (LDS) + row-major split -> Xhi/Xlo.
// Phase B: W = T · Θ via 3-term split-bf16 MFMA -> Wt (LDS, f32).
// Phase C: transposed+PERMUTED split of Wt -> WVPhi/lo.
//   Position c in each 32-key tile holds key k(c)=((c&7)>>2)*16+(c>>3)*4+(c&3).
// ---------------------------------------------------------------------------
__global__ void __launch_bounds__(256)
presplit(const float* __restrict__ x, const float* __restrict__ theta,
         __bf16* __restrict__ ws)
{
    __shared__ __align__(16) float T[64 * 68];
    __shared__ __align__(16) float Wt[64 * 68];
    const int tid  = threadIdx.x;
    const int lane = tid & 63;
    const int wave = tid >> 6;
    const int l16  = lane & 15;
    const int quad = lane >> 4;
    const int bx   = blockIdx.x;
    const int g    = bx >> 4;
    const int nblk = bx & 15;
    const int bb   = g / NT;
    const int tt   = g - bb * NT;
    const int n0   = nblk * 64;

    __bf16* Xhi  = ws + WXHI  + (size_t)g * 65536;
    __bf16* Xlo  = ws + WXLO  + (size_t)g * 65536;
    __bf16* WPhi = ws + WVPHI + (size_t)g * 65536;
    __bf16* WPlo = ws + WVPLO + (size_t)g * 65536;
    const float* xg = x + (size_t)bb * (NNODE * XROW) + (size_t)tt * ND;

    // ---- Phase A: 64x64 fp32 tile -> T + row-major split ----
    #pragma unroll
    for (int i = 0; i < 4; ++i) {
        int chunk = i * 256 + tid;        // 0..1023
        int n  = chunk >> 4;              // 0..63
        int c4 = (chunk & 15) * 4;        // 0..60
        floatx4 f = *(const floatx4*)(xg + (size_t)(n0 + n) * XROW + c4);
        *(floatx4*)(T + n * 68 + c4) = f;
        bf16x4 h, l;
        #pragma unroll
        for (int j = 0; j < 4; ++j) {
            bfpair p = split1(f[j]); h[j] = p.h; l[j] = p.l;
        }
        *(bf16x4*)(Xhi + (size_t)(n0 + n) * 64 + c4) = h;
        *(bf16x4*)(Xlo + (size_t)(n0 + n) * 64 + c4) = l;
    }
    __syncthreads();

    // ---- Phase B: W = T · Θ (3-term split-bf16 MFMA), wave owns 16 keys ----
    {
        bf16x8 tah[2], tal[2];
        #pragma unroll
        for (int ks = 0; ks < 2; ++ks)
            #pragma unroll
            for (int j = 0; j < 8; ++j) {
                bfpair p = split1(T[(wave*16 + l16)*68 + ks*32 + quad*8 + j]);
                tah[ks][j] = p.h; tal[ks][j] = p.l;
            }
        const floatx4 vz = {0.f, 0.f, 0.f, 0.f};
        #pragma unroll
        for (int ot = 0; ot < 4; ++ot) {
            bf16x8 thb[2], tlb[2];
            #pragma unroll
            for (int ks = 0; ks < 2; ++ks)
                #pragma unroll
                for (int j = 0; j < 8; ++j) {
                    bfpair p = split1(theta[(size_t)(ks*32 + quad*8 + j) * ND
                                            + ot*16 + l16]);
                    thb[ks][j] = p.h; tlb[ks][j] = p.l;
                }
            floatx4 Wc = vz;
            #pragma unroll
            for (int ks = 0; ks < 2; ++ks) {
                Wc = MFMA(tah[ks], thb[ks], Wc);
                Wc = MFMA(tal[ks], thb[ks], Wc);
                Wc = MFMA(tah[ks], tlb[ks], Wc);
            }
            #pragma unroll
            for (int r = 0; r < 4; ++r)
                Wt[(wave*16 + quad*4 + r)*68 + ot*16 + l16] = Wc[r];
        }
    }
    __syncthreads();

    // ---- Phase C: transposed + permuted split of Wt (verified code) ----
    {
        const int o  = tid >> 2;          // 0..63
        const int nc = (tid & 3) * 16;    // 0..48 (dst positions nc..nc+15)
        const int tb = nc & 32;           // 32-key tile base within the 64-blk
        bf16x8 h0, l0, h1, l1;
        #pragma unroll
        for (int j = 0; j < 8; ++j) {
            int c0 = (nc & 31) + j;       // dst position in tile
            int k0 = ((c0 & 7) >> 2) * 16 + (c0 >> 3) * 4 + (c0 & 3);
            bfpair p = split1(Wt[(tb + k0) * 68 + o]);
            h0[j] = p.h; l0[j] = p.l;
            int c1 = (nc & 31) + 8 + j;
            int k1 = ((c1 & 7) >> 2) * 16 + (c1 >> 3) * 4 + (c1 & 3);
            bfpair q = split1(Wt[(tb + k1) * 68 + o]);
            h1[j] = q.h; l1[j] = q.l;
        }
        __bf16* dsth = WPhi + (size_t)o * NNODE + n0 + nc;
        __bf16* dstl = WPlo + (size_t)o * NNODE + n0 + nc;
        *(bf16x8*)dsth = h0; *(bf16x8*)(dsth + 8) = h1;
        *(bf16x8*)dstl = l0; *(bf16x8*)(dstl + 8) = l1;
    }
}

// ---------------------------------------------------------------------------
// spattn13: grid 768 (bx = rblk*96 + g), 256 threads, 4 waves x 32 rows.
// R17 staging; PW delayed one tile (skewed pipeline, P carried in regs).
// ---------------------------------------------------------------------------
__global__ void __launch_bounds__(256, 2)
spattn13(const __bf16* __restrict__ ws, const float* __restrict__ adj,
         float* __restrict__ out)
{
    __shared__ __align__(16) char smem[SMEM13];

    const int tid  = threadIdx.x;
    const int wave = tid >> 6;          // 0..3, owns rows wave*32..+31
    const int lane = tid & 63;
    const int l16  = lane & 15;
    const int quad = lane >> 4;

    // bx = rblk*96 + g: all 8 row-blocks of a g share bx%8 -> same XCD.
    const int bx   = blockIdx.x;
    const int g    = bx % NG;           // 0..95
    const int rblk = bx / NG;           // 0..7
    const int bb   = g / NT;
    const int tt   = g - bb * NT;
    const int row0 = rblk * 128;

    const __bf16* xh  = ws + WXHI  + (size_t)g * 65536;
    const __bf16* xl  = ws + WXLO  + (size_t)g * 65536;
    const __bf16* wph = ws + WVPHI + (size_t)g * 65536;
    const __bf16* wpl = ws + WVPLO + (size_t)g * 65536;

    // staging source maps (per-lane, tile-invariant), R17-verified.
    const int kc   = (lane & 7) ^ (lane >> 3);       // inverse-swizzled chunk
    const int krow = (wave << 3) + (lane >> 3);      // K row (0..31)
    const int wo   = ((wave << 3) + (lane >> 3)) * 2 + ((kc & 4) >> 2);
    const int wko  = (kc & 3) * 8;

    // ---- Q fragments b128 from row-major split arrays (B operand) ----
    bf16x8 qhi[2][2], qlo[2][2];
    #pragma unroll
    for (int mt = 0; mt < 2; ++mt) {
        const __bf16* q0 = xh + (size_t)(row0 + wave*32 + mt*16 + l16) * 64 + quad*8;
        const __bf16* q1 = xl + (size_t)(row0 + wave*32 + mt*16 + l16) * 64 + quad*8;
        #pragma unroll
        for (int ks = 0; ks < 2; ++ks) {
            qhi[mt][ks] = *(const bf16x8*)(q0 + ks*32);
            qlo[mt][ks] = *(const bf16x8*)(q1 + ks*32);
        }
    }

    const floatx4 vzero = {0.f, 0.f, 0.f, 0.f};
    floatx4 acc[2][4];
    #pragma unroll
    for (int mt = 0; mt < 2; ++mt)
        #pragma unroll
        for (int dt = 0; dt < 4; ++dt)
            acc[mt][dt] = vzero;
    float lpart[2] = {0.f, 0.f};        // per-lane partial: q = l16 (per mt)
    bf16x8 pah_prev[2], pal_prev[2];    // P of the previous tile (carried)

    // prologue: async-stage tile 0 into buffer 0
    gld16(xh  + (size_t)krow * 64 + kc*8, smem + OKH + wave*1024);
    gld16(xl  + (size_t)krow * 64 + kc*8, smem + OKL + wave*1024);
    gld16(wph + (size_t)wo * NNODE + wko, smem + OWH + wave*1024);
    gld16(wpl + (size_t)wo * NNODE + wko, smem + OWL + wave*1024);

    int bK = 0, bW = 2, bL = 1;         // read-K, read-W(prev), load-dest
    for (int ct = 0; ct < 32; ++ct) {
        const int key0 = ct * 32;
        __syncthreads();   // drains in-flight gloads (tile ct visible);
                           // all waves done with last iter's reads
        if (ct < 31) {     // async-stage tile ct+1 into buf[bL]
            const int nk = key0 + 32;
            char* wb = smem + bL * BUF2;
            gld16(xh  + (size_t)(nk + krow) * 64 + kc*8, wb + OKH + wave*1024);
            gld16(xl  + (size_t)(nk + krow) * 64 + kc*8, wb + OKL + wave*1024);
            gld16(wph + (size_t)wo * NNODE + nk + wko,   wb + OWH + wave*1024);
            gld16(wpl + (size_t)wo * NNODE + nk + wko,   wb + OWL + wave*1024);
        }
        // adj: float4 loads; lane l16 = q-row, quad*4+r = key within nt-tile
        floatx4 av[2][2];
        #pragma unroll
        for (int mt = 0; mt < 2; ++mt)
            #pragma unroll
            for (int nt = 0; nt < 2; ++nt)
                av[mt][nt] = *(const floatx4*)(adj
                    + (size_t)(row0 + wave*32 + mt*16 + l16) * NNODE
                    + key0 + nt*16 + quad*4);

        // ---- S^T = K Q^T (swapped operands; 3-term split bf16) ----
        char* rbK = smem + bK * BUF2;
        __bf16* Khi = (__bf16*)(rbK + OKH);
        __bf16* Klo = (__bf16*)(rbK + OKL);
        floatx4 S[2][2] = {{vzero, vzero}, {vzero, vzero}};   // [mt][nt]
        __builtin_amdgcn_s_setprio(1);
        #pragma unroll
        for (int ks = 0; ks < 2; ++ks) {
            #pragma unroll
            for (int nt = 0; nt < 2; ++nt) {
                const int kch = (((ks*4 + quad) ^ (l16 & 7))) * 8;
                bf16x8 ah = *(const bf16x8*)(Khi + (nt*16 + l16)*64 + kch);
                bf16x8 al = *(const bf16x8*)(Klo + (nt*16 + l16)*64 + kch);
                #pragma unroll
                for (int mt = 0; mt < 2; ++mt) {
                    S[mt][nt] = MFMA(ah, qhi[mt][ks], S[mt][nt]);
                    S[mt][nt] = MFMA(ah, qlo[mt][ks], S[mt][nt]);
                    S[mt][nt] = MFMA(al, qhi[mt][ks], S[mt][nt]);
                }
            }
        }
        __builtin_amdgcn_s_setprio(0);

        // ---- PW(ct-1): independent of exp(ct) -> compiler co-schedules
        //      these MFMAs with the exp/split VALU below ----
        if (ct > 0) {
            char* rbW = smem + bW * BUF2;
            __bf16* Whi = (__bf16*)(rbW + OWH);
            __bf16* Wlo = (__bf16*)(rbW + OWL);
            __builtin_amdgcn_s_setprio(1);
            #pragma unroll
            for (int dt = 0; dt < 4; ++dt) {
                const int wmr = dt*8 + (l16 >> 1);
                const int wch = ((((l16 & 1)*4 + quad) ^ ((l16 >> 1) & 7))) * 8;
                bf16x8 wvh = *(const bf16x8*)(Whi + wmr*64 + wch);
                bf16x8 wvl = *(const bf16x8*)(Wlo + wmr*64 + wch);
                #pragma unroll
                for (int mt = 0; mt < 2; ++mt) {
                    acc[mt][dt] = MFMA(pah_prev[mt], wvh, acc[mt][dt]);
                    acc[mt][dt] = MFMA(pal_prev[mt], wvh, acc[mt][dt]);
                    acc[mt][dt] = MFMA(pah_prev[mt], wvl, acc[mt][dt]);
                }
            }
            __builtin_amdgcn_s_setprio(0);
        }

        // ---- exp2 + adj-mask + split -> becomes P(ct) for next iter ----
        #pragma unroll
        for (int mt = 0; mt < 2; ++mt)
            #pragma unroll
            for (int nt = 0; nt < 2; ++nt)
                #pragma unroll
                for (int r = 0; r < 4; ++r) {
                    float w = __builtin_amdgcn_exp2f(S[mt][nt][r] * QSCALE);
                    lpart[mt] += w;
                    bfpair pp = split1(av[mt][nt][r] * w);
                    pah_prev[mt][nt*4 + r] = pp.h;
                    pal_prev[mt][nt*4 + r] = pp.l;
                }

        // rotate buffers: bK' = bL, bW' = bK, bL' = old bW
        int tmp = bW; bW = bK; bK = bL; bL = tmp;
    }

    // ---- tail: PW(31) (buf[bW] intact: no loads issued at ct=31) ----
    {
        char* rbW = smem + bW * BUF2;
        __bf16* Whi = (__bf16*)(rbW + OWH);
        __bf16* Wlo = (__bf16*)(rbW + OWL);
        #pragma unroll
        for (int dt = 0; dt < 4; ++dt) {
            const int wmr = dt*8 + (l16 >> 1);
            const int wch = ((((l16 & 1)*4 + quad) ^ ((l16 >> 1) & 7))) * 8;
            bf16x8 wvh = *(const bf16x8*)(Whi + wmr*64 + wch);
            bf16x8 wvl = *(const bf16x8*)(Wlo + wmr*64 + wch);
            #pragma unroll
            for (int mt = 0; mt < 2; ++mt) {
                acc[mt][dt] = MFMA(pah_prev[mt], wvh, acc[mt][dt]);
                acc[mt][dt] = MFMA(pal_prev[mt], wvh, acc[mt][dt]);
                acc[mt][dt] = MFMA(pah_prev[mt], wvl, acc[mt][dt]);
            }
        }
    }

    // ---- denominator: reduce across quads (each lane has q = l16) ----
    float linv[2][4];
    #pragma unroll
    for (int mt = 0; mt < 2; ++mt) {
        float lv = lpart[mt];
        lv += __shfl_xor(lv, 16);
        lv += __shfl_xor(lv, 32);           // every lane: full sum for q=l16
        #pragma unroll
        for (int r = 0; r < 4; ++r)
            linv[mt][r] = 1.0f / __shfl(lv, quad*4 + r);
    }

    // ---- store: out = relu(acc * linv) — no epilogue matmul needed ----
    float* obase = out + (size_t)bb * (NNODE * XROW) + tt * ND;
    #pragma unroll
    for (int mt = 0; mt < 2; ++mt)
        #pragma unroll
        for (int dt = 0; dt < 4; ++dt)
            #pragma unroll
            for (int r = 0; r < 4; ++r) {
                float v = acc[mt][dt][r] * linv[mt][r];
                obase[(size_t)(row0 + wave*32 + mt*16 + quad*4 + r) * XROW + dt*16 + l16]
                    = v > 0.f ? v : 0.f;
            }
}

// ---------------------------------------------------------------------------
// Fallback: verified R5 kernel (used only if workspace is too small).
// ---------------------------------------------------------------------------
__global__ void __launch_bounds__(256, 2)
spattn_fb(const float* __restrict__ x, const float* __restrict__ adj,
          const float* __restrict__ theta, float* __restrict__ out)
{
    __shared__ __align__(16) char smem[SMEM_FB];
    __bf16* Khi = (__bf16*)(smem + OFF_KHI);
    __bf16* Klo = (__bf16*)(smem + OFF_KLO);
    __bf16* Vhi = (__bf16*)(smem + OFF_VHI);
    __bf16* Vlo = (__bf16*)(smem + OFF_VLO);
    float*  Pm  = (float*)(smem + OFF_P);

    const int tid  = threadIdx.x;
    const int wave = tid >> 6;
    const int lane = tid & 63;
    const int l16  = lane & 15;
    const int quad = lane >> 4;

    const int bx   = blockIdx.x;
    const int g    = bx >> 3;
    const int rblk = bx & 7;
    const int bb   = g / NT;
    const int tt   = g - bb * NT;
    const int row0 = rblk * 128;

    const float* xbase = x + (size_t)bb * (NNODE * XROW) + tt * ND;

    bf16x8 qhi[2][2], qlo[2][2];
    #pragma unroll
    for (int mt = 0; mt < 2; ++mt) {
        const float* qsrc = xbase + (size_t)(row0 + wave*32 + mt*16 + l16) * XROW;
        #pragma unroll
        for (int ks = 0; ks < 2; ++ks) {
            floatx4 f0 = *(const floatx4*)(qsrc + ks*32 + quad*8);
            floatx4 f1 = *(const floatx4*)(qsrc + ks*32 + quad*8 + 4);
            #pragma unroll
            for (int i = 0; i < 4; ++i) {
                bfpair p0 = split1(f0[i]*QSCALE);
                qhi[mt][ks][i]   = p0.h; qlo[mt][ks][i]   = p0.l;
                bfpair p1 = split1(f1[i]*QSCALE);
                qhi[mt][ks][4+i] = p1.h; qlo[mt][ks][4+i] = p1.l;
            }
        }
    }

    const floatx4 vzero = {0.f, 0.f, 0.f, 0.f};
    floatx4 acc[2][4];
    #pragma unroll
    for (int mt = 0; mt < 2; ++mt)
        #pragma unroll
        for (int dt = 0; dt < 4; ++dt)
            acc[mt][dt] = vzero;
    float lpart[2][4] = {{0.f,0.f,0.f,0.f},{0.f,0.f,0.f,0.f}};

    const int skey = tid >> 3;
    const int sd0  = (tid & 7) * 8;
    const int svd  = tid >> 2;
    const int svk0 = (tid & 3) * 8;
    floatx4 kf0, kf1;
    float vf[8];

    {
        const float* ksrc = xbase + (size_t)skey * XROW + sd0;
        kf0 = *(const floatx4*)ksrc;
        kf1 = *(const floatx4*)(ksrc + 4);
        const float* vsrc = xbase + (size_t)svk0 * XROW + svd;
        #pragma unroll
        for (int i = 0; i < 8; ++i) vf[i] = vsrc[i * XROW];
    }

    for (int ct = 0; ct < 32; ++ct) {
        const int key0 = ct * 32;
        __syncthreads();
        {
            bf16x8 h, l;
            #pragma unroll
            for (int i = 0; i < 4; ++i) {
                bfpair p0 = split1(kf0[i]); h[i]   = p0.h; l[i]   = p0.l;
                bfpair p1 = split1(kf1[i]); h[4+i] = p1.h; l[4+i] = p1.l;
            }
            *(bf16x8*)(Khi + skey*KSTRIDE + sd0) = h;
            *(bf16x8*)(Klo + skey*KSTRIDE + sd0) = l;
            bf16x8 vh, vl;
            #pragma unroll
            for (int i = 0; i < 8; ++i) {
                bfpair p = split1(vf[i]); vh[i] = p.h; vl[i] = p.l;
            }
            *(bf16x8*)(Vhi + svd*VSTRIDE + svk0) = vh;
            *(bf16x8*)(Vlo + svd*VSTRIDE + svk0) = vl;
        }
        __syncthreads();
        if (ct < 31) {
            const int nk = key0 + 32;
            const float* ksrc = xbase + (size_t)(nk + skey) * XROW + sd0;
            kf0 = *(const floatx4*)ksrc;
            kf1 = *(const floatx4*)(ksrc + 4);
            const float* vsrc = xbase + (size_t)(nk + svk0) * XROW + svd;
            #pragma unroll
            for (int i = 0; i < 8; ++i) vf[i] = vsrc[i * XROW];
        }
        float av[2][2][4];
        #pragma unroll
        for (int mt = 0; mt < 2; ++mt)
            #pragma unroll
            for (int nt = 0; nt < 2; ++nt)
                #pragma unroll
                for (int r = 0; r < 4; ++r)
                    av[mt][nt][r] = adj[(size_t)(row0 + wave*32 + mt*16 + quad*4 + r) * NNODE
                                        + key0 + nt*16 + l16];

        floatx4 S[2][2] = {{vzero, vzero}, {vzero, vzero}};
        #pragma unroll
        for (int ks = 0; ks < 2; ++ks) {
            #pragma unroll
            for (int nt = 0; nt < 2; ++nt) {
                bf16x8 bh = *(const bf16x8*)(Khi + (nt*16 + l16)*KSTRIDE + ks*32 + quad*8);
                bf16x8 bl = *(const bf16x8*)(Klo + (nt*16 + l16)*KSTRIDE + ks*32 + quad*8);
                #pragma unroll
                for (int mt = 0; mt < 2; ++mt) {
                    S[mt][nt] = MFMA(qhi[mt][ks], bh, S[mt][nt]);
                    S[mt][nt] = MFMA(qlo[mt][ks], bh, S[mt][nt]);
                    S[mt][nt] = MFMA(qhi[mt][ks], bl, S[mt][nt]);
                }
            }
        }
        #pragma unroll
        for (int mt = 0; mt < 2; ++mt)
            #pragma unroll
            for (int nt = 0; nt < 2; ++nt)
                #pragma unroll
                for (int r = 0; r < 4; ++r) {
                    float w = __builtin_amdgcn_exp2f(S[mt][nt][r]);
                    lpart[mt][r] += w;
                    Pm[(wave*32 + mt*16 + quad*4 + r)*PSTRIDE + nt*16 + l16] = av[mt][nt][r] * w;
                }
        bf16x8 pah[2], pal[2];
        #pragma unroll
        for (int mt = 0; mt < 2; ++mt) {
            const float* pp = Pm + (wave*32 + mt*16 + l16)*PSTRIDE + quad*8;
            floatx4 p0 = *(const floatx4*)pp;
            floatx4 p1 = *(const floatx4*)(pp + 4);
            #pragma unroll
            for (int i = 0; i < 4; ++i) {
                bfpair q0 = split1(p0[i]); pah[mt][i]   = q0.h; pal[mt][i]   = q0.l;
                bfpair q1 = split1(p1[i]); pah[mt][4+i] = q1.h; pal[mt][4+i] = q1.l;
            }
        }
        #pragma unroll
        for (int dt = 0; dt < 4; ++dt) {
            bf16x8 vh = *(const bf16x8*)(Vhi + (dt*16 + l16)*VSTRIDE + quad*8);
            bf16x8 vl = *(const bf16x8*)(Vlo + (dt*16 + l16)*VSTRIDE + quad*8);
            #pragma unroll
            for (int mt = 0; mt < 2; ++mt) {
                acc[mt][dt] = MFMA(pah[mt], vh, acc[mt][dt]);
                acc[mt][dt] = MFMA(pal[mt], vh, acc[mt][dt]);
                acc[mt][dt] = MFMA(pah[mt], vl, acc[mt][dt]);
            }
        }
    }

    float linv[2][4];
    #pragma unroll
    for (int mt = 0; mt < 2; ++mt)
        #pragma unroll
        for (int r = 0; r < 4; ++r) {
            float lv = lpart[mt][r];
            lv += __shfl_xor(lv, 1);
            lv += __shfl_xor(lv, 2);
            lv += __shfl_xor(lv, 4);
            lv += __shfl_xor(lv, 8);
            linv[mt][r] = 1.0f / lv;
        }

    __syncthreads();
    float* AG = (float*)smem;
    #pragma unroll
    for (int mt = 0; mt < 2; ++mt)
        #pragma unroll
        for (int dt = 0; dt < 4; ++dt)
            #pragma unroll
            for (int r = 0; r < 4; ++r)
                AG[(wave*32 + mt*16 + quad*4 + r)*AGSTRIDE + dt*16 + l16]
                    = acc[mt][dt][r] * linv[mt][r];

    bf16x8 th[4][2], tl[4][2];
    #pragma unroll
    for (int ot = 0; ot < 4; ++ot)
        #pragma unroll
        for (int ks = 0; ks < 2; ++ks)
            #pragma unroll
            for (int j = 0; j < 8; ++j) {
                float tv = theta[(ks*32 + quad*8 + j)*ND + ot*16 + l16];
                bfpair p = split1(tv);
                th[ot][ks][j] = p.h; tl[ot][ks][j] = p.l;
            }

    floatx4 oacc[2][4];
    #pragma unroll
    for (int mt = 0; mt < 2; ++mt)
        #pragma unroll
        for (int ot = 0; ot < 4; ++ot)
            oacc[mt][ot] = vzero;
    __syncthreads();
    #pragma unroll
    for (int ks = 0; ks < 2; ++ks) {
        bf16x8 ah[2], al[2];
        #pragma unroll
        for (int mt = 0; mt < 2; ++mt) {
            const float* ap = AG + (wave*32 + mt*16 + l16)*AGSTRIDE + ks*32 + quad*8;
            floatx4 a0 = *(const floatx4*)ap;
            floatx4 a1 = *(const floatx4*)(ap + 4);
            #pragma unroll
            for (int i = 0; i < 4; ++i) {
                bfpair q0 = split1(a0[i]); ah[mt][i]   = q0.h; al[mt][i]   = q0.l;
                bfpair q1 = split1(a1[i]); ah[mt][4+i] = q1.h; al[mt][4+i] = q1.l;
            }
        }
        #pragma unroll
        for (int ot = 0; ot < 4; ++ot)
            #pragma unroll
            for (int mt = 0; mt < 2; ++mt) {
                oacc[mt][ot] = MFMA(ah[mt], th[ot][ks], oacc[mt][ot]);
                oacc[mt][ot] = MFMA(al[mt], th[ot][ks], oacc[mt][ot]);
                oacc[mt][ot] = MFMA(ah[mt], tl[ot][ks], oacc[mt][ot]);
            }
    }

    float* obase = out + (size_t)bb * (NNODE * XROW) + tt * ND;
    #pragma unroll
    for (int mt = 0; mt < 2; ++mt)
        #pragma unroll
        for (int ot = 0; ot < 4; ++ot)
            #pragma unroll
            for (int r = 0; r < 4; ++r) {
                float v = oacc[mt][ot][r];
                obase[(size_t)(row0 + wave*32 + mt*16 + quad*4 + r) * XROW + ot*16 + l16]
                    = v > 0.f ? v : 0.f;
            }
}

extern "C" void kernel_launch(void* const* d_in, const int* in_sizes, int n_in,
                              void* d_out, int out_size, void* d_ws, size_t ws_size,
                              hipStream_t stream) {
    (void)in_sizes; (void)n_in; (void)out_size;
    const float* x     = (const float*)d_in[0];
    const float* adj   = (const float*)d_in[1];
    const float* theta = (const float*)d_in[2];
    float* out = (float*)d_out;
    if (d_ws != nullptr && ws_size >= WS_BYTES) {
        __bf16* ws = (__bf16*)d_ws;
        presplit<<<dim3(1536), dim3(256), 0, stream>>>(x, theta, ws);
        spattn13<<<dim3(768), dim3(256), 0, stream>>>(ws, adj, out);
    } else {
        spattn_fb<<<dim3(768), dim3(256), 0, stream>>>(x, adj, theta, out);
    }
}

// Round 14
// 166.441 us; speedup vs baseline: 1.1470x; 1.0047x over previous
//
#include <hip/hip_runtime.h>

// PositionWiseSpatialAttention — fused flash-style kernel, MI355X gfx950.
//
// R19 = R17 verbatim (best verified: main 88.1us, 0 bank conflicts, VGPR 72,
// no spill). R18's skewed pipeline was flat-to-negative: PW(ct-1) reads
// pah_prev which exp(ct) overwrites -> WAR on 16 regs; allocator (proven
// rename-averse in R14/R16) serializes anyway; 3rd LDS buffer cost +23%
// FETCH. Reverted.
//
// Final structure: presplit folds theta into W = X·Θ and emits {hi,lo}
// bf16 row-major X + permuted-transposed W; spattn12 runs swapped-QK^T
// with register P, async global_load_lds staging (linear dest +
// inverse-swizzled source + XOR-swizzled reads, rule #21 -> 0 conflicts),
// double-buffered, 1 barrier/iter, setprio around MFMA clusters, no
// epilogue (out = relu(acc*linv) direct).
// Session ledger: 117us (R5 start) -> 101 (R9 merge) -> 93.7 (R13 fold+dbuf)
// -> 92.0 (R15 setprio) -> 88.1 (R17 gld_lds). Serialization-breaking
// attempts all refuted: occupancy (R12), LDS-bypass (R8/R11), reg-hoist
// (R14/R16 spill), skew (R18).

#define NB    8
#define NT    12
#define NNODE 1024
#define ND    64
#define XROW  768   /* NT*ND: stride between consecutive n for fixed (b,t) */
#define NG    96    /* NB*NT */

typedef __bf16 bf16x8 __attribute__((ext_vector_type(8)));
typedef __bf16 bf16x4 __attribute__((ext_vector_type(4)));
typedef float  floatx4 __attribute__((ext_vector_type(4)));

#define MFMA(a,b,c) __builtin_amdgcn_mfma_f32_16x16x32_bf16((a),(b),(c),0,0,0)

#define QSCALE 0.18033688011112042f   /* 0.125 * log2(e) */

// Per-buffer LDS layout (bytes): 4 linear 4KB arrays, swizzled content.
#define OKH 0
#define OKL 4096
#define OWH 8192
#define OWL 12288
#define BUF2 16384
#define SMEM12 (2 * BUF2)                 /* 32768 */
// fallback (R5) LDS map
#define KSTRIDE 72
#define VSTRIDE 40
#define PSTRIDE 36
#define AGSTRIDE 68
#define OFF_KHI 0
#define OFF_KLO 4608
#define OFF_VHI 9216
#define OFF_VLO 14336
#define OFF_P   19456
#define SMEM_FB (19456 + 128*PSTRIDE*4)   /* 37888 */

// workspace element offsets (__bf16 units)
#define WXHI  0          /* [96][1024][64] row-major hi           */
#define WXLO  6291456
#define WVPHI 12582912   /* [96][64 o][1024] W^T permuted hi       */
#define WVPLO 18874368
#define WS_BYTES 50348032ULL

struct bfpair { __bf16 h, l; };

// error-compensated split: hi = RNE(f) via native fptrunc, lo = RNE(f - hi).
__device__ __forceinline__ bfpair split1(float f) {
    bfpair r;
    __bf16 hb = (__bf16)f;
    float hf = __builtin_bit_cast(float,
                   (unsigned)__builtin_bit_cast(unsigned short, hb) << 16);
    r.h = hb;
    r.l = (__bf16)(f - hf);
    return r;
}

// async global->LDS, 16B per lane; dest = wave-uniform base + lane*16.
__device__ __forceinline__ void gld16(const __bf16* g, char* l) {
    __builtin_amdgcn_global_load_lds(
        (const __attribute__((address_space(1))) void*)g,
        (__attribute__((address_space(3))) void*)l, 16, 0, 0);
}

// ---------------------------------------------------------------------------
// presplit: grid 1536 (96 g x 16 n-blocks), 256 threads. (R13, verified)
// Phase A: x tile -> T (LDS) + row-major split -> Xhi/Xlo.
// Phase B: W = T · Θ via 3-term split-bf16 MFMA -> Wt (LDS, f32).
// Phase C: transposed+PERMUTED split of Wt -> WVPhi/lo.
//   Position c in each 32-key tile holds key k(c)=((c&7)>>2)*16+(c>>3)*4+(c&3).
// ---------------------------------------------------------------------------
__global__ void __launch_bounds__(256)
presplit(const float* __restrict__ x, const float* __restrict__ theta,
         __bf16* __restrict__ ws)
{
    __shared__ __align__(16) float T[64 * 68];
    __shared__ __align__(16) float Wt[64 * 68];
    const int tid  = threadIdx.x;
    const int lane = tid & 63;
    const int wave = tid >> 6;
    const int l16  = lane & 15;
    const int quad = lane >> 4;
    const int bx   = blockIdx.x;
    const int g    = bx >> 4;
    const int nblk = bx & 15;
    const int bb   = g / NT;
    const int tt   = g - bb * NT;
    const int n0   = nblk * 64;

    __bf16* Xhi  = ws + WXHI  + (size_t)g * 65536;
    __bf16* Xlo  = ws + WXLO  + (size_t)g * 65536;
    __bf16* WPhi = ws + WVPHI + (size_t)g * 65536;
    __bf16* WPlo = ws + WVPLO + (size_t)g * 65536;
    const float* xg = x + (size_t)bb * (NNODE * XROW) + (size_t)tt * ND;

    // ---- Phase A: 64x64 fp32 tile -> T + row-major split ----
    #pragma unroll
    for (int i = 0; i < 4; ++i) {
        int chunk = i * 256 + tid;        // 0..1023
        int n  = chunk >> 4;              // 0..63
        int c4 = (chunk & 15) * 4;        // 0..60
        floatx4 f = *(const floatx4*)(xg + (size_t)(n0 + n) * XROW + c4);
        *(floatx4*)(T + n * 68 + c4) = f;
        bf16x4 h, l;
        #pragma unroll
        for (int j = 0; j < 4; ++j) {
            bfpair p = split1(f[j]); h[j] = p.h; l[j] = p.l;
        }
        *(bf16x4*)(Xhi + (size_t)(n0 + n) * 64 + c4) = h;
        *(bf16x4*)(Xlo + (size_t)(n0 + n) * 64 + c4) = l;
    }
    __syncthreads();

    // ---- Phase B: W = T · Θ (3-term split-bf16 MFMA), wave owns 16 keys ----
    {
        bf16x8 tah[2], tal[2];
        #pragma unroll
        for (int ks = 0; ks < 2; ++ks)
            #pragma unroll
            for (int j = 0; j < 8; ++j) {
                bfpair p = split1(T[(wave*16 + l16)*68 + ks*32 + quad*8 + j]);
                tah[ks][j] = p.h; tal[ks][j] = p.l;
            }
        const floatx4 vz = {0.f, 0.f, 0.f, 0.f};
        #pragma unroll
        for (int ot = 0; ot < 4; ++ot) {
            bf16x8 thb[2], tlb[2];
            #pragma unroll
            for (int ks = 0; ks < 2; ++ks)
                #pragma unroll
                for (int j = 0; j < 8; ++j) {
                    bfpair p = split1(theta[(size_t)(ks*32 + quad*8 + j) * ND
                                            + ot*16 + l16]);
                    thb[ks][j] = p.h; tlb[ks][j] = p.l;
                }
            floatx4 Wc = vz;
            #pragma unroll
            for (int ks = 0; ks < 2; ++ks) {
                Wc = MFMA(tah[ks], thb[ks], Wc);
                Wc = MFMA(tal[ks], thb[ks], Wc);
                Wc = MFMA(tah[ks], tlb[ks], Wc);
            }
            #pragma unroll
            for (int r = 0; r < 4; ++r)
                Wt[(wave*16 + quad*4 + r)*68 + ot*16 + l16] = Wc[r];
        }
    }
    __syncthreads();

    // ---- Phase C: transposed + permuted split of Wt (verified code) ----
    {
        const int o  = tid >> 2;          // 0..63
        const int nc = (tid & 3) * 16;    // 0..48 (dst positions nc..nc+15)
        const int tb = nc & 32;           // 32-key tile base within the 64-blk
        bf16x8 h0, l0, h1, l1;
        #pragma unroll
        for (int j = 0; j < 8; ++j) {
            int c0 = (nc & 31) + j;       // dst position in tile
            int k0 = ((c0 & 7) >> 2) * 16 + (c0 >> 3) * 4 + (c0 & 3);
            bfpair p = split1(Wt[(tb + k0) * 68 + o]);
            h0[j] = p.h; l0[j] = p.l;
            int c1 = (nc & 31) + 8 + j;
            int k1 = ((c1 & 7) >> 2) * 16 + (c1 >> 3) * 4 + (c1 & 3);
            bfpair q = split1(Wt[(tb + k1) * 68 + o]);
            h1[j] = q.h; l1[j] = q.l;
        }
        __bf16* dsth = WPhi + (size_t)o * NNODE + n0 + nc;
        __bf16* dstl = WPlo + (size_t)o * NNODE + n0 + nc;
        *(bf16x8*)dsth = h0; *(bf16x8*)(dsth + 8) = h1;
        *(bf16x8*)dstl = l0; *(bf16x8*)(dstl + 8) = l1;
    }
}

// ---------------------------------------------------------------------------
// spattn12: grid 768 (bx = rblk*96 + g), 256 threads, 4 waves x 32 rows.
// R15 loop; staging via async global_load_lds with source/read swizzle.
// ---------------------------------------------------------------------------
__global__ void __launch_bounds__(256, 3)
spattn12(const __bf16* __restrict__ ws, const float* __restrict__ adj,
         float* __restrict__ out)
{
    __shared__ __align__(16) char smem[SMEM12];

    const int tid  = threadIdx.x;
    const int wave = tid >> 6;          // 0..3, owns rows wave*32..+31
    const int lane = tid & 63;
    const int l16  = lane & 15;
    const int quad = lane >> 4;

    // bx = rblk*96 + g: all 8 row-blocks of a g share bx%8 -> same XCD.
    const int bx   = blockIdx.x;
    const int g    = bx % NG;           // 0..95
    const int rblk = bx / NG;           // 0..7
    const int bb   = g / NT;
    const int tt   = g - bb * NT;
    const int row0 = rblk * 128;

    const __bf16* xh  = ws + WXHI  + (size_t)g * 65536;
    const __bf16* xl  = ws + WXLO  + (size_t)g * 65536;
    const __bf16* wph = ws + WVPHI + (size_t)g * 65536;
    const __bf16* wpl = ws + WVPLO + (size_t)g * 65536;

    // staging source maps (per-lane, tile-invariant).
    // K: lane covers (row = 8*wave + lane>>3, dest chunk lane&7); the data
    //    placed there is source chunk (lane&7)^(row&7), row&7 = lane>>3.
    const int kc   = (lane & 7) ^ (lane >> 3);       // K/W source chunk
    const int krow = (wave << 3) + (lane >> 3);      // K row (0..31)
    // W: macro = 8*wave + lane>>3 covers o = 2*macro + (kc>>2), key (kc&3)*8
    const int wo   = ((wave << 3) + (lane >> 3)) * 2 + ((kc & 4) >> 2);
    const int wko  = (kc & 3) * 8;

    // ---- Q fragments b128 from row-major split arrays (B operand) ----
    bf16x8 qhi[2][2], qlo[2][2];
    #pragma unroll
    for (int mt = 0; mt < 2; ++mt) {
        const __bf16* q0 = xh + (size_t)(row0 + wave*32 + mt*16 + l16) * 64 + quad*8;
        const __bf16* q1 = xl + (size_t)(row0 + wave*32 + mt*16 + l16) * 64 + quad*8;
        #pragma unroll
        for (int ks = 0; ks < 2; ++ks) {
            qhi[mt][ks] = *(const bf16x8*)(q0 + ks*32);
            qlo[mt][ks] = *(const bf16x8*)(q1 + ks*32);
        }
    }

    const floatx4 vzero = {0.f, 0.f, 0.f, 0.f};
    floatx4 acc[2][4];
    #pragma unroll
    for (int mt = 0; mt < 2; ++mt)
        #pragma unroll
        for (int dt = 0; dt < 4; ++dt)
            acc[mt][dt] = vzero;
    float lpart[2] = {0.f, 0.f};        // per-lane partial: q = l16 (per mt)

    // prologue: async-stage tile 0 into buffer 0 (drained by first barrier)
    {
        char* b0 = smem;
        gld16(xh  + (size_t)krow * 64 + kc*8,          b0 + OKH + wave*1024);
        gld16(xl  + (size_t)krow * 64 + kc*8,          b0 + OKL + wave*1024);
        gld16(wph + (size_t)wo * NNODE + wko,          b0 + OWH + wave*1024);
        gld16(wpl + (size_t)wo * NNODE + wko,          b0 + OWL + wave*1024);
    }

    int cur = 0;
    for (int ct = 0; ct < 32; ++ct) {
        const int key0 = ct * 32;
        __syncthreads();   // drains in-flight gloads (tile ct now visible);
                           // all waves done reading buf[cur^1]
        if (ct < 31) {     // async-stage tile ct+1 into the dead buffer
            const int nk = key0 + 32;
            char* wb = smem + (cur ^ 1) * BUF2;
            gld16(xh  + (size_t)(nk + krow) * 64 + kc*8, wb + OKH + wave*1024);
            gld16(xl  + (size_t)(nk + krow) * 64 + kc*8, wb + OKL + wave*1024);
            gld16(wph + (size_t)wo * NNODE + nk + wko,   wb + OWH + wave*1024);
            gld16(wpl + (size_t)wo * NNODE + nk + wko,   wb + OWL + wave*1024);
        }
        // adj: float4 loads; lane l16 = q-row, quad*4+r = key within nt-tile
        floatx4 av[2][2];
        #pragma unroll
        for (int mt = 0; mt < 2; ++mt)
            #pragma unroll
            for (int nt = 0; nt < 2; ++nt)
                av[mt][nt] = *(const floatx4*)(adj
                    + (size_t)(row0 + wave*32 + mt*16 + l16) * NNODE
                    + key0 + nt*16 + quad*4);

        char* rb = smem + cur * BUF2;
        __bf16* Khi = (__bf16*)(rb + OKH);
        __bf16* Klo = (__bf16*)(rb + OKL);
        __bf16* Whi = (__bf16*)(rb + OWH);
        __bf16* Wlo = (__bf16*)(rb + OWL);

        // ---- S^T = K Q^T (swapped operands; 3-term split bf16) ----
        // Output: col = q = l16, row = key = nt*16 + quad*4 + r.
        // K read swizzle: chunk (ks*4+quad) stored at chunk^(row&7).
        floatx4 S[2][2] = {{vzero, vzero}, {vzero, vzero}};   // [mt][nt]
        __builtin_amdgcn_s_setprio(1);
        #pragma unroll
        for (int ks = 0; ks < 2; ++ks) {
            #pragma unroll
            for (int nt = 0; nt < 2; ++nt) {
                const int kch = (((ks*4 + quad) ^ (l16 & 7))) * 8;
                bf16x8 ah = *(const bf16x8*)(Khi + (nt*16 + l16)*64 + kch);
                bf16x8 al = *(const bf16x8*)(Klo + (nt*16 + l16)*64 + kch);
                #pragma unroll
                for (int mt = 0; mt < 2; ++mt) {
                    S[mt][nt] = MFMA(ah, qhi[mt][ks], S[mt][nt]);
                    S[mt][nt] = MFMA(ah, qlo[mt][ks], S[mt][nt]);
                    S[mt][nt] = MFMA(al, qhi[mt][ks], S[mt][nt]);
                }
            }
        }
        __builtin_amdgcn_s_setprio(0);

        // ---- exp2 + adj-mask + split, ALL in registers ----
        bf16x8 pah[2], pal[2];
        #pragma unroll
        for (int mt = 0; mt < 2; ++mt)
            #pragma unroll
            for (int nt = 0; nt < 2; ++nt)
                #pragma unroll
                for (int r = 0; r < 4; ++r) {
                    float w = __builtin_amdgcn_exp2f(S[mt][nt][r] * QSCALE);
                    lpart[mt] += w;
                    bfpair pp = split1(av[mt][nt][r] * w);
                    pah[mt][nt*4 + r] = pp.h;
                    pal[mt][nt*4 + r] = pp.l;
                }

        // ---- acc += P . W (3-term split) ----
        // W read swizzle: macro m = dt*8 + (l16>>1); source chunk
        // c = (l16&1)*4 + quad stored at c^(m&7), m&7 = (l16>>1)&7.
        __builtin_amdgcn_s_setprio(1);
        #pragma unroll
        for (int dt = 0; dt < 4; ++dt) {
            const int wmr = dt*8 + (l16 >> 1);
            const int wch = ((((l16 & 1)*4 + quad) ^ ((l16 >> 1) & 7))) * 8;
            bf16x8 wvh = *(const bf16x8*)(Whi + wmr*64 + wch);
            bf16x8 wvl = *(const bf16x8*)(Wlo + wmr*64 + wch);
            #pragma unroll
            for (int mt = 0; mt < 2; ++mt) {
                acc[mt][dt] = MFMA(pah[mt], wvh, acc[mt][dt]);
                acc[mt][dt] = MFMA(pal[mt], wvh, acc[mt][dt]);
                acc[mt][dt] = MFMA(pah[mt], wvl, acc[mt][dt]);
            }
        }
        __builtin_amdgcn_s_setprio(0);
        cur ^= 1;
    }

    // ---- denominator: reduce across quads (each lane has q = l16) ----
    float linv[2][4];
    #pragma unroll
    for (int mt = 0; mt < 2; ++mt) {
        float lv = lpart[mt];
        lv += __shfl_xor(lv, 16);
        lv += __shfl_xor(lv, 32);           // every lane: full sum for q=l16
        #pragma unroll
        for (int r = 0; r < 4; ++r)
            linv[mt][r] = 1.0f / __shfl(lv, quad*4 + r);
    }

    // ---- store: out = relu(acc * linv) — no epilogue matmul needed ----
    float* obase = out + (size_t)bb * (NNODE * XROW) + tt * ND;
    #pragma unroll
    for (int mt = 0; mt < 2; ++mt)
        #pragma unroll
        for (int dt = 0; dt < 4; ++dt)
            #pragma unroll
            for (int r = 0; r < 4; ++r) {
                float v = acc[mt][dt][r] * linv[mt][r];
                obase[(size_t)(row0 + wave*32 + mt*16 + quad*4 + r) * XROW + dt*16 + l16]
                    = v > 0.f ? v : 0.f;
            }
}

// ---------------------------------------------------------------------------
// Fallback: verified R5 kernel (used only if workspace is too small).
// ---------------------------------------------------------------------------
__global__ void __launch_bounds__(256, 2)
spattn_fb(const float* __restrict__ x, const float* __restrict__ adj,
          const float* __restrict__ theta, float* __restrict__ out)
{
    __shared__ __align__(16) char smem[SMEM_FB];
    __bf16* Khi = (__bf16*)(smem + OFF_KHI);
    __bf16* Klo = (__bf16*)(smem + OFF_KLO);
    __bf16* Vhi = (__bf16*)(smem + OFF_VHI);
    __bf16* Vlo = (__bf16*)(smem + OFF_VLO);
    float*  Pm  = (float*)(smem + OFF_P);

    const int tid  = threadIdx.x;
    const int wave = tid >> 6;
    const int lane = tid & 63;
    const int l16  = lane & 15;
    const int quad = lane >> 4;

    const int bx   = blockIdx.x;
    const int g    = bx >> 3;
    const int rblk = bx & 7;
    const int bb   = g / NT;
    const int tt   = g - bb * NT;
    const int row0 = rblk * 128;

    const float* xbase = x + (size_t)bb * (NNODE * XROW) + tt * ND;

    bf16x8 qhi[2][2], qlo[2][2];
    #pragma unroll
    for (int mt = 0; mt < 2; ++mt) {
        const float* qsrc = xbase + (size_t)(row0 + wave*32 + mt*16 + l16) * XROW;
        #pragma unroll
        for (int ks = 0; ks < 2; ++ks) {
            floatx4 f0 = *(const floatx4*)(qsrc + ks*32 + quad*8);
            floatx4 f1 = *(const floatx4*)(qsrc + ks*32 + quad*8 + 4);
            #pragma unroll
            for (int i = 0; i < 4; ++i) {
                bfpair p0 = split1(f0[i]*QSCALE);
                qhi[mt][ks][i]   = p0.h; qlo[mt][ks][i]   = p0.l;
                bfpair p1 = split1(f1[i]*QSCALE);
                qhi[mt][ks][4+i] = p1.h; qlo[mt][ks][4+i] = p1.l;
            }
        }
    }

    const floatx4 vzero = {0.f, 0.f, 0.f, 0.f};
    floatx4 acc[2][4];
    #pragma unroll
    for (int mt = 0; mt < 2; ++mt)
        #pragma unroll
        for (int dt = 0; dt < 4; ++dt)
            acc[mt][dt] = vzero;
    float lpart[2][4] = {{0.f,0.f,0.f,0.f},{0.f,0.f,0.f,0.f}};

    const int skey = tid >> 3;
    const int sd0  = (tid & 7) * 8;
    const int svd  = tid >> 2;
    const int svk0 = (tid & 3) * 8;
    floatx4 kf0, kf1;
    float vf[8];

    {
        const float* ksrc = xbase + (size_t)skey * XROW + sd0;
        kf0 = *(const floatx4*)ksrc;
        kf1 = *(const floatx4*)(ksrc + 4);
        const float* vsrc = xbase + (size_t)svk0 * XROW + svd;
        #pragma unroll
        for (int i = 0; i < 8; ++i) vf[i] = vsrc[i * XROW];
    }

    for (int ct = 0; ct < 32; ++ct) {
        const int key0 = ct * 32;
        __syncthreads();
        {
            bf16x8 h, l;
            #pragma unroll
            for (int i = 0; i < 4; ++i) {
                bfpair p0 = split1(kf0[i]); h[i]   = p0.h; l[i]   = p0.l;
                bfpair p1 = split1(kf1[i]); h[4+i] = p1.h; l[4+i] = p1.l;
            }
            *(bf16x8*)(Khi + skey*KSTRIDE + sd0) = h;
            *(bf16x8*)(Klo + skey*KSTRIDE + sd0) = l;
            bf16x8 vh, vl;
            #pragma unroll
            for (int i = 0; i < 8; ++i) {
                bfpair p = split1(vf[i]); vh[i] = p.h; vl[i] = p.l;
            }
            *(bf16x8*)(Vhi + svd*VSTRIDE + svk0) = vh;
            *(bf16x8*)(Vlo + svd*VSTRIDE + svk0) = vl;
        }
        __syncthreads();
        if (ct < 31) {
            const int nk = key0 + 32;
            const float* ksrc = xbase + (size_t)(nk + skey) * XROW + sd0;
            kf0 = *(const floatx4*)ksrc;
            kf1 = *(const floatx4*)(ksrc + 4);
            const float* vsrc = xbase + (size_t)(nk + svk0) * XROW + svd;
            #pragma unroll
            for (int i = 0; i < 8; ++i) vf[i] = vsrc[i * XROW];
        }
        float av[2][2][4];
        #pragma unroll
        for (int mt = 0; mt < 2; ++mt)
            #pragma unroll
            for (int nt = 0; nt < 2; ++nt)
                #pragma unroll
                for (int r = 0; r < 4; ++r)
                    av[mt][nt][r] = adj[(size_t)(row0 + wave*32 + mt*16 + quad*4 + r) * NNODE
                                        + key0 + nt*16 + l16];

        floatx4 S[2][2] = {{vzero, vzero}, {vzero, vzero}};
        #pragma unroll
        for (int ks = 0; ks < 2; ++ks) {
            #pragma unroll
            for (int nt = 0; nt < 2; ++nt) {
                bf16x8 bh = *(const bf16x8*)(Khi + (nt*16 + l16)*KSTRIDE + ks*32 + quad*8);
                bf16x8 bl = *(const bf16x8*)(Klo + (nt*16 + l16)*KSTRIDE + ks*32 + quad*8);
                #pragma unroll
                for (int mt = 0; mt < 2; ++mt) {
                    S[mt][nt] = MFMA(qhi[mt][ks], bh, S[mt][nt]);
                    S[mt][nt] = MFMA(qlo[mt][ks], bh, S[mt][nt]);
                    S[mt][nt] = MFMA(qhi[mt][ks], bl, S[mt][nt]);
                }
            }
        }
        #pragma unroll
        for (int mt = 0; mt < 2; ++mt)
            #pragma unroll
            for (int nt = 0; nt < 2; ++nt)
                #pragma unroll
                for (int r = 0; r < 4; ++r) {
                    float w = __builtin_amdgcn_exp2f(S[mt][nt][r]);
                    lpart[mt][r] += w;
                    Pm[(wave*32 + mt*16 + quad*4 + r)*PSTRIDE + nt*16 + l16] = av[mt][nt][r] * w;
                }
        bf16x8 pah[2], pal[2];
        #pragma unroll
        for (int mt = 0; mt < 2; ++mt) {
            const float* pp = Pm + (wave*32 + mt*16 + l16)*PSTRIDE + quad*8;
            floatx4 p0 = *(const floatx4*)pp;
            floatx4 p1 = *(const floatx4*)(pp + 4);
            #pragma unroll
            for (int i = 0; i < 4; ++i) {
                bfpair q0 = split1(p0[i]); pah[mt][i]   = q0.h; pal[mt][i]   = q0.l;
                bfpair q1 = split1(p1[i]); pah[mt][4+i] = q1.h; pal[mt][4+i] = q1.l;
            }
        }
        #pragma unroll
        for (int dt = 0; dt < 4; ++dt) {
            bf16x8 vh = *(const bf16x8*)(Vhi + (dt*16 + l16)*VSTRIDE + quad*8);
            bf16x8 vl = *(const bf16x8*)(Vlo + (dt*16 + l16)*VSTRIDE + quad*8);
            #pragma unroll
            for (int mt = 0; mt < 2; ++mt) {
                acc[mt][dt] = MFMA(pah[mt], vh, acc[mt][dt]);
                acc[mt][dt] = MFMA(pal[mt], vh, acc[mt][dt]);
                acc[mt][dt] = MFMA(pah[mt], vl, acc[mt][dt]);
            }
        }
    }

    float linv[2][4];
    #pragma unroll
    for (int mt = 0; mt < 2; ++mt)
        #pragma unroll
        for (int r = 0; r < 4; ++r) {
            float lv = lpart[mt][r];
            lv += __shfl_xor(lv, 1);
            lv += __shfl_xor(lv, 2);
            lv += __shfl_xor(lv, 4);
            lv += __shfl_xor(lv, 8);
            linv[mt][r] = 1.0f / lv;
        }

    __syncthreads();
    float* AG = (float*)smem;
    #pragma unroll
    for (int mt = 0; mt < 2; ++mt)
        #pragma unroll
        for (int dt = 0; dt < 4; ++dt)
            #pragma unroll
            for (int r = 0; r < 4; ++r)
                AG[(wave*32 + mt*16 + quad*4 + r)*AGSTRIDE + dt*16 + l16]
                    = acc[mt][dt][r] * linv[mt][r];

    bf16x8 th[4][2], tl[4][2];
    #pragma unroll
    for (int ot = 0; ot < 4; ++ot)
        #pragma unroll
        for (int ks = 0; ks < 2; ++ks)
            #pragma unroll
            for (int j = 0; j < 8; ++j) {
                float tv = theta[(ks*32 + quad*8 + j)*ND + ot*16 + l16];
                bfpair p = split1(tv);
                th[ot][ks][j] = p.h; tl[ot][ks][j] = p.l;
            }

    floatx4 oacc[2][4];
    #pragma unroll
    for (int mt = 0; mt < 2; ++mt)
        #pragma unroll
        for (int ot = 0; ot < 4; ++ot)
            oacc[mt][ot] = vzero;
    __syncthreads();
    #pragma unroll
    for (int ks = 0; ks < 2; ++ks) {
        bf16x8 ah[2], al[2];
        #pragma unroll
        for (int mt = 0; mt < 2; ++mt) {
            const float* ap = AG + (wave*32 + mt*16 + l16)*AGSTRIDE + ks*32 + quad*8;
            floatx4 a0 = *(const floatx4*)ap;
            floatx4 a1 = *(const floatx4*)(ap + 4);
            #pragma unroll
            for (int i = 0; i < 4; ++i) {
                bfpair q0 = split1(a0[i]); ah[mt][i]   = q0.h; al[mt][i]   = q0.l;
                bfpair q1 = split1(a1[i]); ah[mt][4+i] = q1.h; al[mt][4+i] = q1.l;
            }
        }
        #pragma unroll
        for (int ot = 0; ot < 4; ++ot)
            #pragma unroll
            for (int mt = 0; mt < 2; ++mt) {
                oacc[mt][ot] = MFMA(ah[mt], th[ot][ks], oacc[mt][ot]);
                oacc[mt][ot] = MFMA(al[mt], th[ot][ks], oacc[mt][ot]);
                oacc[mt][ot] = MFMA(ah[mt], tl[ot][ks], oacc[mt][ot]);
            }
    }

    float* obase = out + (size_t)bb * (NNODE * XROW) + tt * ND;
    #pragma unroll
    for (int mt = 0; mt < 2; ++mt)
        #pragma unroll
        for (int ot = 0; ot < 4; ++ot)
            #pragma unroll
            for (int r = 0; r < 4; ++r) {
                float v = oacc[mt][ot][r];
                obase[(size_t)(row0 + wave*32 + mt*16 + quad*4 + r) * XROW + ot*16 + l16]
                    = v > 0.f ? v : 0.f;
            }
}

extern "C" void kernel_launch(void* const* d_in, const int* in_sizes, int n_in,
                              void* d_out, int out_size, void* d_ws, size_t ws_size,
                              hipStream_t stream) {
    (void)in_sizes; (void)n_in; (void)out_size;
    const float* x     = (const float*)d_in[0];
    const float* adj   = (const float*)d_in[1];
    const float* theta = (const float*)d_in[2];
    float* out = (float*)d_out;
    if (d_ws != nullptr && ws_size >= WS_BYTES) {
        __bf16* ws = (__bf16*)d_ws;
        presplit<<<dim3(1536), dim3(256), 0, stream>>>(x, theta, ws);
        spattn12<<<dim3(768), dim3(256), 0, stream>>>(ws, adj, out);
    } else {
        spattn_fb<<<dim3(768), dim3(256), 0, stream>>>(x, adj, theta, out);
    }
}

// Round 15
// 166.192 us; speedup vs baseline: 1.1487x; 1.0015x over previous
//
#include <hip/hip_runtime.h>

// PositionWiseSpatialAttention — fused flash-style kernel, MI355X gfx950.
//
// R20 = FINAL = R17/R19 (best verified, reproduced twice: main 88.1/88.3us,
// 0 LDS bank conflicts, VGPR 72, no spill, bench 166.4us vs 171-173 baseline).
//
// Structure: presplit folds theta into W = X·Θ and emits {hi,lo} bf16
// row-major X + permuted-transposed W; spattn12 runs swapped-QK^T with
// register-resident P, async global_load_lds staging (linear dest +
// inverse-swizzled global source + XOR-swizzled LDS reads, rule #21 ->
// zero conflicts), double-buffered K/W, 1 barrier/iter, setprio around
// MFMA clusters, no epilogue (out = relu(acc*linv) stored directly).
//
// Session ledger (main-dispatch us): 117 (R5) -> 101 (R9: presplit ws +
// copy staging + XCD map) -> 103.8 (R10: register P, neutral) -> 93.7
// (R13: theta-fold + dbuf 1-barrier) -> 92.0 (R15: setprio) -> 88.1
// (R17: global_load_lds + swizzle, conflicts 7.9M -> 0).
// Refuted levers (all measured): occupancy up (R6 spill, R12 28->58% but
// slower), K/V LDS bypass (R8/R11 latency-exposed), register hoists
// (R14/R16 scratch-spill despite headroom), skewed PW pipeline (R18
// WAR-serialized). Binding constraint: the per-iteration dependency chain
// at 3 waves/SIMD with an allocator that spills rather than renames —
// a compiler/structure limit, not a pipe roofline (HBM 12%, MFMA ~11%,
// LDS ~35%, VALU ~38%).

#define NB    8
#define NT    12
#define NNODE 1024
#define ND    64
#define XROW  768   /* NT*ND: stride between consecutive n for fixed (b,t) */
#define NG    96    /* NB*NT */

typedef __bf16 bf16x8 __attribute__((ext_vector_type(8)));
typedef __bf16 bf16x4 __attribute__((ext_vector_type(4)));
typedef float  floatx4 __attribute__((ext_vector_type(4)));

#define MFMA(a,b,c) __builtin_amdgcn_mfma_f32_16x16x32_bf16((a),(b),(c),0,0,0)

#define QSCALE 0.18033688011112042f   /* 0.125 * log2(e) */

// Per-buffer LDS layout (bytes): 4 linear 4KB arrays, swizzled content.
#define OKH 0
#define OKL 4096
#define OWH 8192
#define OWL 12288
#define BUF2 16384
#define SMEM12 (2 * BUF2)                 /* 32768 */
// fallback (R5) LDS map
#define KSTRIDE 72
#define VSTRIDE 40
#define PSTRIDE 36
#define AGSTRIDE 68
#define OFF_KHI 0
#define OFF_KLO 4608
#define OFF_VHI 9216
#define OFF_VLO 14336
#define OFF_P   19456
#define SMEM_FB (19456 + 128*PSTRIDE*4)   /* 37888 */

// workspace element offsets (__bf16 units)
#define WXHI  0          /* [96][1024][64] row-major hi           */
#define WXLO  6291456
#define WVPHI 12582912   /* [96][64 o][1024] W^T permuted hi       */
#define WVPLO 18874368
#define WS_BYTES 50348032ULL

struct bfpair { __bf16 h, l; };

// error-compensated split: hi = RNE(f) via native fptrunc, lo = RNE(f - hi).
__device__ __forceinline__ bfpair split1(float f) {
    bfpair r;
    __bf16 hb = (__bf16)f;
    float hf = __builtin_bit_cast(float,
                   (unsigned)__builtin_bit_cast(unsigned short, hb) << 16);
    r.h = hb;
    r.l = (__bf16)(f - hf);
    return r;
}

// async global->LDS, 16B per lane; dest = wave-uniform base + lane*16.
__device__ __forceinline__ void gld16(const __bf16* g, char* l) {
    __builtin_amdgcn_global_load_lds(
        (const __attribute__((address_space(1))) void*)g,
        (__attribute__((address_space(3))) void*)l, 16, 0, 0);
}

// ---------------------------------------------------------------------------
// presplit: grid 1536 (96 g x 16 n-blocks), 256 threads. (R13, verified)
// Phase A: x tile -> T (LDS) + row-major split -> Xhi/Xlo.
// Phase B: W = T · Θ via 3-term split-bf16 MFMA -> Wt (LDS, f32).
// Phase C: transposed+PERMUTED split of Wt -> WVPhi/lo.
//   Position c in each 32-key tile holds key k(c)=((c&7)>>2)*16+(c>>3)*4+(c&3).
// ---------------------------------------------------------------------------
__global__ void __launch_bounds__(256)
presplit(const float* __restrict__ x, const float* __restrict__ theta,
         __bf16* __restrict__ ws)
{
    __shared__ __align__(16) float T[64 * 68];
    __shared__ __align__(16) float Wt[64 * 68];
    const int tid  = threadIdx.x;
    const int lane = tid & 63;
    const int wave = tid >> 6;
    const int l16  = lane & 15;
    const int quad = lane >> 4;
    const int bx   = blockIdx.x;
    const int g    = bx >> 4;
    const int nblk = bx & 15;
    const int bb   = g / NT;
    const int tt   = g - bb * NT;
    const int n0   = nblk * 64;

    __bf16* Xhi  = ws + WXHI  + (size_t)g * 65536;
    __bf16* Xlo  = ws + WXLO  + (size_t)g * 65536;
    __bf16* WPhi = ws + WVPHI + (size_t)g * 65536;
    __bf16* WPlo = ws + WVPLO + (size_t)g * 65536;
    const float* xg = x + (size_t)bb * (NNODE * XROW) + (size_t)tt * ND;

    // ---- Phase A: 64x64 fp32 tile -> T + row-major split ----
    #pragma unroll
    for (int i = 0; i < 4; ++i) {
        int chunk = i * 256 + tid;        // 0..1023
        int n  = chunk >> 4;              // 0..63
        int c4 = (chunk & 15) * 4;        // 0..60
        floatx4 f = *(const floatx4*)(xg + (size_t)(n0 + n) * XROW + c4);
        *(floatx4*)(T + n * 68 + c4) = f;
        bf16x4 h, l;
        #pragma unroll
        for (int j = 0; j < 4; ++j) {
            bfpair p = split1(f[j]); h[j] = p.h; l[j] = p.l;
        }
        *(bf16x4*)(Xhi + (size_t)(n0 + n) * 64 + c4) = h;
        *(bf16x4*)(Xlo + (size_t)(n0 + n) * 64 + c4) = l;
    }
    __syncthreads();

    // ---- Phase B: W = T · Θ (3-term split-bf16 MFMA), wave owns 16 keys ----
    {
        bf16x8 tah[2], tal[2];
        #pragma unroll
        for (int ks = 0; ks < 2; ++ks)
            #pragma unroll
            for (int j = 0; j < 8; ++j) {
                bfpair p = split1(T[(wave*16 + l16)*68 + ks*32 + quad*8 + j]);
                tah[ks][j] = p.h; tal[ks][j] = p.l;
            }
        const floatx4 vz = {0.f, 0.f, 0.f, 0.f};
        #pragma unroll
        for (int ot = 0; ot < 4; ++ot) {
            bf16x8 thb[2], tlb[2];
            #pragma unroll
            for (int ks = 0; ks < 2; ++ks)
                #pragma unroll
                for (int j = 0; j < 8; ++j) {
                    bfpair p = split1(theta[(size_t)(ks*32 + quad*8 + j) * ND
                                            + ot*16 + l16]);
                    thb[ks][j] = p.h; tlb[ks][j] = p.l;
                }
            floatx4 Wc = vz;
            #pragma unroll
            for (int ks = 0; ks < 2; ++ks) {
                Wc = MFMA(tah[ks], thb[ks], Wc);
                Wc = MFMA(tal[ks], thb[ks], Wc);
                Wc = MFMA(tah[ks], tlb[ks], Wc);
            }
            #pragma unroll
            for (int r = 0; r < 4; ++r)
                Wt[(wave*16 + quad*4 + r)*68 + ot*16 + l16] = Wc[r];
        }
    }
    __syncthreads();

    // ---- Phase C: transposed + permuted split of Wt (verified code) ----
    {
        const int o  = tid >> 2;          // 0..63
        const int nc = (tid & 3) * 16;    // 0..48 (dst positions nc..nc+15)
        const int tb = nc & 32;           // 32-key tile base within the 64-blk
        bf16x8 h0, l0, h1, l1;
        #pragma unroll
        for (int j = 0; j < 8; ++j) {
            int c0 = (nc & 31) + j;       // dst position in tile
            int k0 = ((c0 & 7) >> 2) * 16 + (c0 >> 3) * 4 + (c0 & 3);
            bfpair p = split1(Wt[(tb + k0) * 68 + o]);
            h0[j] = p.h; l0[j] = p.l;
            int c1 = (nc & 31) + 8 + j;
            int k1 = ((c1 & 7) >> 2) * 16 + (c1 >> 3) * 4 + (c1 & 3);
            bfpair q = split1(Wt[(tb + k1) * 68 + o]);
            h1[j] = q.h; l1[j] = q.l;
        }
        __bf16* dsth = WPhi + (size_t)o * NNODE + n0 + nc;
        __bf16* dstl = WPlo + (size_t)o * NNODE + n0 + nc;
        *(bf16x8*)dsth = h0; *(bf16x8*)(dsth + 8) = h1;
        *(bf16x8*)dstl = l0; *(bf16x8*)(dstl + 8) = l1;
    }
}

// ---------------------------------------------------------------------------
// spattn12: grid 768 (bx = rblk*96 + g), 256 threads, 4 waves x 32 rows.
// Swapped QK^T, register P, async gld_lds staging with source/read swizzle.
// ---------------------------------------------------------------------------
__global__ void __launch_bounds__(256, 3)
spattn12(const __bf16* __restrict__ ws, const float* __restrict__ adj,
         float* __restrict__ out)
{
    __shared__ __align__(16) char smem[SMEM12];

    const int tid  = threadIdx.x;
    const int wave = tid >> 6;          // 0..3, owns rows wave*32..+31
    const int lane = tid & 63;
    const int l16  = lane & 15;
    const int quad = lane >> 4;

    // bx = rblk*96 + g: all 8 row-blocks of a g share bx%8 -> same XCD.
    const int bx   = blockIdx.x;
    const int g    = bx % NG;           // 0..95
    const int rblk = bx / NG;           // 0..7
    const int bb   = g / NT;
    const int tt   = g - bb * NT;
    const int row0 = rblk * 128;

    const __bf16* xh  = ws + WXHI  + (size_t)g * 65536;
    const __bf16* xl  = ws + WXLO  + (size_t)g * 65536;
    const __bf16* wph = ws + WVPHI + (size_t)g * 65536;
    const __bf16* wpl = ws + WVPLO + (size_t)g * 65536;

    // staging source maps (per-lane, tile-invariant).
    // K: lane covers (row = 8*wave + lane>>3, dest chunk lane&7); the data
    //    placed there is source chunk (lane&7)^(row&7), row&7 = lane>>3.
    const int kc   = (lane & 7) ^ (lane >> 3);       // K/W source chunk
    const int krow = (wave << 3) + (lane >> 3);      // K row (0..31)
    // W: macro = 8*wave + lane>>3 covers o = 2*macro + (kc>>2), key (kc&3)*8
    const int wo   = ((wave << 3) + (lane >> 3)) * 2 + ((kc & 4) >> 2);
    const int wko  = (kc & 3) * 8;

    // ---- Q fragments b128 from row-major split arrays (B operand) ----
    bf16x8 qhi[2][2], qlo[2][2];
    #pragma unroll
    for (int mt = 0; mt < 2; ++mt) {
        const __bf16* q0 = xh + (size_t)(row0 + wave*32 + mt*16 + l16) * 64 + quad*8;
        const __bf16* q1 = xl + (size_t)(row0 + wave*32 + mt*16 + l16) * 64 + quad*8;
        #pragma unroll
        for (int ks = 0; ks < 2; ++ks) {
            qhi[mt][ks] = *(const bf16x8*)(q0 + ks*32);
            qlo[mt][ks] = *(const bf16x8*)(q1 + ks*32);
        }
    }

    const floatx4 vzero = {0.f, 0.f, 0.f, 0.f};
    floatx4 acc[2][4];
    #pragma unroll
    for (int mt = 0; mt < 2; ++mt)
        #pragma unroll
        for (int dt = 0; dt < 4; ++dt)
            acc[mt][dt] = vzero;
    float lpart[2] = {0.f, 0.f};        // per-lane partial: q = l16 (per mt)

    // prologue: async-stage tile 0 into buffer 0 (drained by first barrier)
    {
        char* b0 = smem;
        gld16(xh  + (size_t)krow * 64 + kc*8,          b0 + OKH + wave*1024);
        gld16(xl  + (size_t)krow * 64 + kc*8,          b0 + OKL + wave*1024);
        gld16(wph + (size_t)wo * NNODE + wko,          b0 + OWH + wave*1024);
        gld16(wpl + (size_t)wo * NNODE + wko,          b0 + OWL + wave*1024);
    }

    int cur = 0;
    for (int ct = 0; ct < 32; ++ct) {
        const int key0 = ct * 32;
        __syncthreads();   // drains in-flight gloads (tile ct now visible);
                           // all waves done reading buf[cur^1]
        if (ct < 31) {     // async-stage tile ct+1 into the dead buffer
            const int nk = key0 + 32;
            char* wb = smem + (cur ^ 1) * BUF2;
            gld16(xh  + (size_t)(nk + krow) * 64 + kc*8, wb + OKH + wave*1024);
            gld16(xl  + (size_t)(nk + krow) * 64 + kc*8, wb + OKL + wave*1024);
            gld16(wph + (size_t)wo * NNODE + nk + wko,   wb + OWH + wave*1024);
            gld16(wpl + (size_t)wo * NNODE + nk + wko,   wb + OWL + wave*1024);
        }
        // adj: float4 loads; lane l16 = q-row, quad*4+r = key within nt-tile
        floatx4 av[2][2];
        #pragma unroll
        for (int mt = 0; mt < 2; ++mt)
            #pragma unroll
            for (int nt = 0; nt < 2; ++nt)
                av[mt][nt] = *(const floatx4*)(adj
                    + (size_t)(row0 + wave*32 + mt*16 + l16) * NNODE
                    + key0 + nt*16 + quad*4);

        char* rb = smem + cur * BUF2;
        __bf16* Khi = (__bf16*)(rb + OKH);
        __bf16* Klo = (__bf16*)(rb + OKL);
        __bf16* Whi = (__bf16*)(rb + OWH);
        __bf16* Wlo = (__bf16*)(rb + OWL);

        // ---- S^T = K Q^T (swapped operands; 3-term split bf16) ----
        // Output: col = q = l16, row = key = nt*16 + quad*4 + r.
        // K read swizzle: chunk (ks*4+quad) stored at chunk^(row&7).
        floatx4 S[2][2] = {{vzero, vzero}, {vzero, vzero}};   // [mt][nt]
        __builtin_amdgcn_s_setprio(1);
        #pragma unroll
        for (int ks = 0; ks < 2; ++ks) {
            #pragma unroll
            for (int nt = 0; nt < 2; ++nt) {
                const int kch = (((ks*4 + quad) ^ (l16 & 7))) * 8;
                bf16x8 ah = *(const bf16x8*)(Khi + (nt*16 + l16)*64 + kch);
                bf16x8 al = *(const bf16x8*)(Klo + (nt*16 + l16)*64 + kch);
                #pragma unroll
                for (int mt = 0; mt < 2; ++mt) {
                    S[mt][nt] = MFMA(ah, qhi[mt][ks], S[mt][nt]);
                    S[mt][nt] = MFMA(ah, qlo[mt][ks], S[mt][nt]);
                    S[mt][nt] = MFMA(al, qhi[mt][ks], S[mt][nt]);
                }
            }
        }
        __builtin_amdgcn_s_setprio(0);

        // ---- exp2 + adj-mask + split, ALL in registers ----
        bf16x8 pah[2], pal[2];
        #pragma unroll
        for (int mt = 0; mt < 2; ++mt)
            #pragma unroll
            for (int nt = 0; nt < 2; ++nt)
                #pragma unroll
                for (int r = 0; r < 4; ++r) {
                    float w = __builtin_amdgcn_exp2f(S[mt][nt][r] * QSCALE);
                    lpart[mt] += w;
                    bfpair pp = split1(av[mt][nt][r] * w);
                    pah[mt][nt*4 + r] = pp.h;
                    pal[mt][nt*4 + r] = pp.l;
                }

        // ---- acc += P . W (3-term split) ----
        // W read swizzle: macro m = dt*8 + (l16>>1); source chunk
        // c = (l16&1)*4 + quad stored at c^(m&7), m&7 = (l16>>1)&7.
        __builtin_amdgcn_s_setprio(1);
        #pragma unroll
        for (int dt = 0; dt < 4; ++dt) {
            const int wmr = dt*8 + (l16 >> 1);
            const int wch = ((((l16 & 1)*4 + quad) ^ ((l16 >> 1) & 7))) * 8;
            bf16x8 wvh = *(const bf16x8*)(Whi + wmr*64 + wch);
            bf16x8 wvl = *(const bf16x8*)(Wlo + wmr*64 + wch);
            #pragma unroll
            for (int mt = 0; mt < 2; ++mt) {
                acc[mt][dt] = MFMA(pah[mt], wvh, acc[mt][dt]);
                acc[mt][dt] = MFMA(pal[mt], wvh, acc[mt][dt]);
                acc[mt][dt] = MFMA(pah[mt], wvl, acc[mt][dt]);
            }
        }
        __builtin_amdgcn_s_setprio(0);
        cur ^= 1;
    }

    // ---- denominator: reduce across quads (each lane has q = l16) ----
    float linv[2][4];
    #pragma unroll
    for (int mt = 0; mt < 2; ++mt) {
        float lv = lpart[mt];
        lv += __shfl_xor(lv, 16);
        lv += __shfl_xor(lv, 32);           // every lane: full sum for q=l16
        #pragma unroll
        for (int r = 0; r < 4; ++r)
            linv[mt][r] = 1.0f / __shfl(lv, quad*4 + r);
    }

    // ---- store: out = relu(acc * linv) — no epilogue matmul needed ----
    float* obase = out + (size_t)bb * (NNODE * XROW) + tt * ND;
    #pragma unroll
    for (int mt = 0; mt < 2; ++mt)
        #pragma unroll
        for (int dt = 0; dt < 4; ++dt)
            #pragma unroll
            for (int r = 0; r < 4; ++r) {
                float v = acc[mt][dt][r] * linv[mt][r];
                obase[(size_t)(row0 + wave*32 + mt*16 + quad*4 + r) * XROW + dt*16 + l16]
                    = v > 0.f ? v : 0.f;
            }
}

// ---------------------------------------------------------------------------
// Fallback: verified R5 kernel (used only if workspace is too small).
// ---------------------------------------------------------------------------
__global__ void __launch_bounds__(256, 2)
spattn_fb(const float* __restrict__ x, const float* __restrict__ adj,
          const float* __restrict__ theta, float* __restrict__ out)
{
    __shared__ __align__(16) char smem[SMEM_FB];
    __bf16* Khi = (__bf16*)(smem + OFF_KHI);
    __bf16* Klo = (__bf16*)(smem + OFF_KLO);
    __bf16* Vhi = (__bf16*)(smem + OFF_VHI);
    __bf16* Vlo = (__bf16*)(smem + OFF_VLO);
    float*  Pm  = (float*)(smem + OFF_P);

    const int tid  = threadIdx.x;
    const int wave = tid >> 6;
    const int lane = tid & 63;
    const int l16  = lane & 15;
    const int quad = lane >> 4;

    const int bx   = blockIdx.x;
    const int g    = bx >> 3;
    const int rblk = bx & 7;
    const int bb   = g / NT;
    const int tt   = g - bb * NT;
    const int row0 = rblk * 128;

    const float* xbase = x + (size_t)bb * (NNODE * XROW) + tt * ND;

    bf16x8 qhi[2][2], qlo[2][2];
    #pragma unroll
    for (int mt = 0; mt < 2; ++mt) {
        const float* qsrc = xbase + (size_t)(row0 + wave*32 + mt*16 + l16) * XROW;
        #pragma unroll
        for (int ks = 0; ks < 2; ++ks) {
            floatx4 f0 = *(const floatx4*)(qsrc + ks*32 + quad*8);
            floatx4 f1 = *(const floatx4*)(qsrc + ks*32 + quad*8 + 4);
            #pragma unroll
            for (int i = 0; i < 4; ++i) {
                bfpair p0 = split1(f0[i]*QSCALE);
                qhi[mt][ks][i]   = p0.h; qlo[mt][ks][i]   = p0.l;
                bfpair p1 = split1(f1[i]*QSCALE);
                qhi[mt][ks][4+i] = p1.h; qlo[mt][ks][4+i] = p1.l;
            }
        }
    }

    const floatx4 vzero = {0.f, 0.f, 0.f, 0.f};
    floatx4 acc[2][4];
    #pragma unroll
    for (int mt = 0; mt < 2; ++mt)
        #pragma unroll
        for (int dt = 0; dt < 4; ++dt)
            acc[mt][dt] = vzero;
    float lpart[2][4] = {{0.f,0.f,0.f,0.f},{0.f,0.f,0.f,0.f}};

    const int skey = tid >> 3;
    const int sd0  = (tid & 7) * 8;
    const int svd  = tid >> 2;
    const int svk0 = (tid & 3) * 8;
    floatx4 kf0, kf1;
    float vf[8];

    {
        const float* ksrc = xbase + (size_t)skey * XROW + sd0;
        kf0 = *(const floatx4*)ksrc;
        kf1 = *(const floatx4*)(ksrc + 4);
        const float* vsrc = xbase + (size_t)svk0 * XROW + svd;
        #pragma unroll
        for (int i = 0; i < 8; ++i) vf[i] = vsrc[i * XROW];
    }

    for (int ct = 0; ct < 32; ++ct) {
        const int key0 = ct * 32;
        __syncthreads();
        {
            bf16x8 h, l;
            #pragma unroll
            for (int i = 0; i < 4; ++i) {
                bfpair p0 = split1(kf0[i]); h[i]   = p0.h; l[i]   = p0.l;
                bfpair p1 = split1(kf1[i]); h[4+i] = p1.h; l[4+i] = p1.l;
            }
            *(bf16x8*)(Khi + skey*KSTRIDE + sd0) = h;
            *(bf16x8*)(Klo + skey*KSTRIDE + sd0) = l;
            bf16x8 vh, vl;
            #pragma unroll
            for (int i = 0; i < 8; ++i) {
                bfpair p = split1(vf[i]); vh[i] = p.h; vl[i] = p.l;
            }
            *(bf16x8*)(Vhi + svd*VSTRIDE + svk0) = vh;
            *(bf16x8*)(Vlo + svd*VSTRIDE + svk0) = vl;
        }
        __syncthreads();
        if (ct < 31) {
            const int nk = key0 + 32;
            const float* ksrc = xbase + (size_t)(nk + skey) * XROW + sd0;
            kf0 = *(const floatx4*)ksrc;
            kf1 = *(const floatx4*)(ksrc + 4);
            const float* vsrc = xbase + (size_t)(nk + svk0) * XROW + svd;
            #pragma unroll
            for (int i = 0; i < 8; ++i) vf[i] = vsrc[i * XROW];
        }
        float av[2][2][4];
        #pragma unroll
        for (int mt = 0; mt < 2; ++mt)
            #pragma unroll
            for (int nt = 0; nt < 2; ++nt)
                #pragma unroll
                for (int r = 0; r < 4; ++r)
                    av[mt][nt][r] = adj[(size_t)(row0 + wave*32 + mt*16 + quad*4 + r) * NNODE
                                        + key0 + nt*16 + l16];

        floatx4 S[2][2] = {{vzero, vzero}, {vzero, vzero}};
        #pragma unroll
        for (int ks = 0; ks < 2; ++ks) {
            #pragma unroll
            for (int nt = 0; nt < 2; ++nt) {
                bf16x8 bh = *(const bf16x8*)(Khi + (nt*16 + l16)*KSTRIDE + ks*32 + quad*8);
                bf16x8 bl = *(const bf16x8*)(Klo + (nt*16 + l16)*KSTRIDE + ks*32 + quad*8);
                #pragma unroll
                for (int mt = 0; mt < 2; ++mt) {
                    S[mt][nt] = MFMA(qhi[mt][ks], bh, S[mt][nt]);
                    S[mt][nt] = MFMA(qlo[mt][ks], bh, S[mt][nt]);
                    S[mt][nt] = MFMA(qhi[mt][ks], bl, S[mt][nt]);
                }
            }
        }
        #pragma unroll
        for (int mt = 0; mt < 2; ++mt)
            #pragma unroll
            for (int nt = 0; nt < 2; ++nt)
                #pragma unroll
                for (int r = 0; r < 4; ++r) {
                    float w = __builtin_amdgcn_exp2f(S[mt][nt][r]);
                    lpart[mt][r] += w;
                    Pm[(wave*32 + mt*16 + quad*4 + r)*PSTRIDE + nt*16 + l16] = av[mt][nt][r] * w;
                }
        bf16x8 pah[2], pal[2];
        #pragma unroll
        for (int mt = 0; mt < 2; ++mt) {
            const float* pp = Pm + (wave*32 + mt*16 + l16)*PSTRIDE + quad*8;
            floatx4 p0 = *(const floatx4*)pp;
            floatx4 p1 = *(const floatx4*)(pp + 4);
            #pragma unroll
            for (int i = 0; i < 4; ++i) {
                bfpair q0 = split1(p0[i]); pah[mt][i]   = q0.h; pal[mt][i]   = q0.l;
                bfpair q1 = split1(p1[i]); pah[mt][4+i] = q1.h; pal[mt][4+i] = q1.l;
            }
        }
        #pragma unroll
        for (int dt = 0; dt < 4; ++dt) {
            bf16x8 vh = *(const bf16x8*)(Vhi + (dt*16 + l16)*VSTRIDE + quad*8);
            bf16x8 vl = *(const bf16x8*)(Vlo + (dt*16 + l16)*VSTRIDE + quad*8);
            #pragma unroll
            for (int mt = 0; mt < 2; ++mt) {
                acc[mt][dt] = MFMA(pah[mt], vh, acc[mt][dt]);
                acc[mt][dt] = MFMA(pal[mt], vh, acc[mt][dt]);
                acc[mt][dt] = MFMA(pah[mt], vl, acc[mt][dt]);
            }
        }
    }

    float linv[2][4];
    #pragma unroll
    for (int mt = 0; mt < 2; ++mt)
        #pragma unroll
        for (int r = 0; r < 4; ++r) {
            float lv = lpart[mt][r];
            lv += __shfl_xor(lv, 1);
            lv += __shfl_xor(lv, 2);
            lv += __shfl_xor(lv, 4);
            lv += __shfl_xor(lv, 8);
            linv[mt][r] = 1.0f / lv;
        }

    __syncthreads();
    float* AG = (float*)smem;
    #pragma unroll
    for (int mt = 0; mt < 2; ++mt)
        #pragma unroll
        for (int dt = 0; dt < 4; ++dt)
            #pragma unroll
            for (int r = 0; r < 4; ++r)
                AG[(wave*32 + mt*16 + quad*4 + r)*AGSTRIDE + dt*16 + l16]
                    = acc[mt][dt][r] * linv[mt][r];

    bf16x8 th[4][2], tl[4][2];
    #pragma unroll
    for (int ot = 0; ot < 4; ++ot)
        #pragma unroll
        for (int ks = 0; ks < 2; ++ks)
            #pragma unroll
            for (int j = 0; j < 8; ++j) {
                float tv = theta[(ks*32 + quad*8 + j)*ND + ot*16 + l16];
                bfpair p = split1(tv);
                th[ot][ks][j] = p.h; tl[ot][ks][j] = p.l;
            }

    floatx4 oacc[2][4];
    #pragma unroll
    for (int mt = 0; mt < 2; ++mt)
        #pragma unroll
        for (int ot = 0; ot < 4; ++ot)
            oacc[mt][ot] = vzero;
    __syncthreads();
    #pragma unroll
    for (int ks = 0; ks < 2; ++ks) {
        bf16x8 ah[2], al[2];
        #pragma unroll
        for (int mt = 0; mt < 2; ++mt) {
            const float* ap = AG + (wave*32 + mt*16 + l16)*AGSTRIDE + ks*32 + quad*8;
            floatx4 a0 = *(const floatx4*)ap;
            floatx4 a1 = *(const floatx4*)(ap + 4);
            #pragma unroll
            for (int i = 0; i < 4; ++i) {
                bfpair q0 = split1(a0[i]); ah[mt][i]   = q0.h; al[mt][i]   = q0.l;
                bfpair q1 = split1(a1[i]); ah[mt][4+i] = q1.h; al[mt][4+i] = q1.l;
            }
        }
        #pragma unroll
        for (int ot = 0; ot < 4; ++ot)
            #pragma unroll
            for (int mt = 0; mt < 2; ++mt) {
                oacc[mt][ot] = MFMA(ah[mt], th[ot][ks], oacc[mt][ot]);
                oacc[mt][ot] = MFMA(al[mt], th[ot][ks], oacc[mt][ot]);
                oacc[mt][ot] = MFMA(ah[mt], tl[ot][ks], oacc[mt][ot]);
            }
    }

    float* obase = out + (size_t)bb * (NNODE * XROW) + tt * ND;
    #pragma unroll
    for (int mt = 0; mt < 2; ++mt)
        #pragma unroll
        for (int ot = 0; ot < 4; ++ot)
            #pragma unroll
            for (int r = 0; r < 4; ++r) {
                float v = oacc[mt][ot][r];
                obase[(size_t)(row0 + wave*32 + mt*16 + quad*4 + r) * XROW + ot*16 + l16]
                    = v > 0.f ? v : 0.f;
            }
}

extern "C" void kernel_launch(void* const* d_in, const int* in_sizes, int n_in,
                              void* d_out, int out_size, void* d_ws, size_t ws_size,
                              hipStream_t stream) {
    (void)in_sizes; (void)n_in; (void)out_size;
    const float* x     = (const float*)d_in[0];
    const float* adj   = (const float*)d_in[1];
    const float* theta = (const float*)d_in[2];
    float* out = (float*)d_out;
    if (d_ws != nullptr && ws_size >= WS_BYTES) {
        __bf16* ws = (__bf16*)d_ws;
        presplit<<<dim3(1536), dim3(256), 0, stream>>>(x, theta, ws);
        spattn12<<<dim3(768), dim3(256), 0, stream>>>(ws, adj, out);
    } else {
        spattn_fb<<<dim3(768), dim3(256), 0, stream>>>(x, adj, theta, out);
    }
}